// Round 2
// baseline (1000.340 us; speedup 1.0000x reference)
//
#include <hip/hip_runtime.h>
#include <math.h>

constexpr int N_ = 30000;
constexpr int E_ = 300000;

__device__ __forceinline__ float4 ldg4(const float* p){ return *reinterpret_cast<const float4*>(p); }

__device__ __forceinline__ unsigned short f2bf(float f){
  union { float f; unsigned int u; } v; v.f = f;
  unsigned int r = v.u + 0x7FFFu + ((v.u >> 16) & 1u);
  return (unsigned short)(r >> 16);
}
__device__ __forceinline__ float bf2f(unsigned short b){
  union { unsigned int u; float f; } v; v.u = ((unsigned int)b) << 16;
  return v.f;
}
__device__ __forceinline__ float sigmoidf_(float x){ return 1.0f/(1.0f + __expf(-x)); }

// ---------------- setup kernels (once per launch) ----------------

__global__ void k_zero(int* __restrict__ row_ptr){
  int i = blockIdx.x*256 + threadIdx.x;
  if (i <= N_) row_ptr[i] = 0;
}

// P[j][h] = sum_c We[j, h*64+c] * a_edge[h, c]
__global__ void k_P(const float* __restrict__ We, const float* __restrict__ a_edge,
                    float* __restrict__ P){
  int t = threadIdx.x; if (t >= 48) return;
  int j = t / 3, h = t % 3;
  float s = 0.f;
  for (int c = 0; c < 64; ++c) s += We[j*192 + h*64 + c] * a_edge[h*64 + c];
  P[j*3 + h] = s;
}

// WihT[k][col] = Wih[col][k]  (Wih is [192,64])
__global__ void k_wt(const float* __restrict__ Wih, const float* __restrict__ Whh,
                     float* __restrict__ WihT, float* __restrict__ WhhT){
  int idx = blockIdx.x*256 + threadIdx.x;
  if (idx < 12288){ int k = idx / 192, col = idx % 192; WihT[idx] = Wih[col*64 + k]; }
  else if (idx < 24576){
    int r = idx - 12288; int k = r / 192, col = r % 192; WhhT[r] = Whh[col*64 + k];
  }
}

// el[e][h] = sum_j edge_attr[e][j] * P[j][h]
__global__ void k_el(const float* __restrict__ edge_attr, const float* __restrict__ P,
                     float* __restrict__ el){
  __shared__ float sP[48];
  int t = threadIdx.x;
  if (t < 48) sP[t] = P[t];
  __syncthreads();
  int e = blockIdx.x*256 + t;
  if (e >= E_) return;
  const float* ea = edge_attr + (size_t)e*16;
  float v[16];
  #pragma unroll
  for (int q = 0; q < 4; ++q){
    float4 f = ldg4(ea + q*4);
    v[q*4+0]=f.x; v[q*4+1]=f.y; v[q*4+2]=f.z; v[q*4+3]=f.w;
  }
  float l0=0.f,l1=0.f,l2=0.f;
  #pragma unroll
  for (int j = 0; j < 16; ++j){
    l0 += v[j]*sP[j*3+0]; l1 += v[j]*sP[j*3+1]; l2 += v[j]*sP[j*3+2];
  }
  el[e*3+0]=l0; el[e*3+1]=l1; el[e*3+2]=l2;
}

__global__ void k_hist(const int* __restrict__ ei, int* __restrict__ row_ptr){
  int e = blockIdx.x*256 + threadIdx.x;
  if (e < E_) atomicAdd(&row_ptr[ei[E_ + e]], 1);
}

// single-block exclusive scan of degrees -> row_ptr, copy to cursor
__global__ __launch_bounds__(1024) void k_scan(int* __restrict__ row_ptr, int* __restrict__ cursor){
  __shared__ int sS[1024];
  int t = threadIdx.x;
  const int CPT = 30; // 1024*30 >= 30000
  int base = t*CPT;
  int sum = 0;
  for (int i = 0; i < CPT; ++i){ int idx = base+i; if (idx < N_) sum += row_ptr[idx]; }
  sS[t] = sum; __syncthreads();
  for (int off = 1; off < 1024; off <<= 1){
    int v = (t >= off) ? sS[t-off] : 0;
    __syncthreads();
    sS[t] += v;
    __syncthreads();
  }
  int run = sS[t] - sum;  // exclusive prefix
  for (int i = 0; i < CPT; ++i){
    int idx = base+i;
    if (idx < N_){ int d = row_ptr[idx]; row_ptr[idx] = run; cursor[idx] = run; run += d; }
  }
  if (t == 1023) row_ptr[N_] = run;
}

__global__ void k_scatter(const int* __restrict__ ei, const float* __restrict__ el,
                          int* __restrict__ cursor, int* __restrict__ src_s,
                          float* __restrict__ el_s){
  int e = blockIdx.x*256 + threadIdx.x;
  if (e >= E_) return;
  int d = ei[E_ + e];
  int p = atomicAdd(&cursor[d], 1);
  src_s[p] = ei[e];
  el_s[p*3+0] = el[e*3+0];
  el_s[p*3+1] = el[e*3+1];
  el_s[p*3+2] = el[e*3+2];
}

// h = x; feats slot 0 = x
__global__ void k_copy(const float* __restrict__ x, float* __restrict__ hbuf,
                       float* __restrict__ feats){
  int idx = blockIdx.x*256 + threadIdx.x;   // one float4 each, 480000 total
  int n = idx >> 4, c4 = (idx & 15) * 4;
  if (n >= N_) return;
  float4 v = ldg4(x + (size_t)n*64 + c4);
  *reinterpret_cast<float4*>(hbuf + (size_t)n*64 + c4) = v;
  *reinterpret_cast<float4*>(feats + (size_t)n*448 + c4) = v;
}

// ---------------- per-step kernels ----------------

// xw = x @ Wg (bf16 out), alpha_src/dst dots; block 0 zeroes bn_stats
__global__ __launch_bounds__(256) void k_xw(
    const float* __restrict__ xsrc,                // row stride 448
    const float* __restrict__ Wg,
    const float* __restrict__ a_src, const float* __restrict__ a_dst,
    unsigned short* __restrict__ xw,
    float* __restrict__ asrc, float* __restrict__ adst,
    float* __restrict__ bn_stats)
{
  __shared__ float sX[64][65];
  const int t = threadIdx.x;
  const int row0 = blockIdx.x * 64;
  if (blockIdx.x == 0 && t < 128) bn_stats[t] = 0.0f;
  {
    int lr = t >> 4, k4 = (t & 15) * 4;
    #pragma unroll
    for (int i = 0; i < 4; ++i){
      int r = lr + i*16, gr = row0 + r;
      float4 v = make_float4(0.f,0.f,0.f,0.f);
      if (gr < N_) v = ldg4(xsrc + (size_t)gr*448 + k4);
      sX[r][k4+0]=v.x; sX[r][k4+1]=v.y; sX[r][k4+2]=v.z; sX[r][k4+3]=v.w;
    }
  }
  __syncthreads();
  const int g = t & 15, rq = t >> 4, c0 = g * 4;
  float acc[4][12];
  for (int i = 0; i < 4; ++i)
    for (int j = 0; j < 12; ++j) acc[i][j] = 0.f;
  #pragma unroll 4
  for (int k = 0; k < 64; ++k){
    const float* wp = Wg + k*192;
    float4 w0 = ldg4(wp + c0), w1 = ldg4(wp + 64 + c0), w2 = ldg4(wp + 128 + c0);
    float wv[12] = {w0.x,w0.y,w0.z,w0.w, w1.x,w1.y,w1.z,w1.w, w2.x,w2.y,w2.z,w2.w};
    #pragma unroll
    for (int i = 0; i < 4; ++i){
      float xv = sX[rq*4+i][k];
      #pragma unroll
      for (int j = 0; j < 12; ++j) acc[i][j] = fmaf(xv, wv[j], acc[i][j]);
    }
  }
  // per-thread slices of a_src / a_dst
  float asw[12], adw[12];
  #pragma unroll
  for (int h = 0; h < 3; ++h){
    float4 a1 = ldg4(a_src + h*64 + c0), a2 = ldg4(a_dst + h*64 + c0);
    asw[h*4+0]=a1.x; asw[h*4+1]=a1.y; asw[h*4+2]=a1.z; asw[h*4+3]=a1.w;
    adw[h*4+0]=a2.x; adw[h*4+1]=a2.y; adw[h*4+2]=a2.z; adw[h*4+3]=a2.w;
  }
  #pragma unroll
  for (int i = 0; i < 4; ++i){
    int gr = row0 + rq*4 + i;
    float ps[3], pd[3];
    #pragma unroll
    for (int h = 0; h < 3; ++h){
      float s = 0.f, d = 0.f;
      #pragma unroll
      for (int cc = 0; cc < 4; ++cc){
        s = fmaf(acc[i][h*4+cc], asw[h*4+cc], s);
        d = fmaf(acc[i][h*4+cc], adw[h*4+cc], d);
      }
      s += __shfl_xor(s,1); s += __shfl_xor(s,2); s += __shfl_xor(s,4); s += __shfl_xor(s,8);
      d += __shfl_xor(d,1); d += __shfl_xor(d,2); d += __shfl_xor(d,4); d += __shfl_xor(d,8);
      ps[h] = s; pd[h] = d;
    }
    if (gr < N_){
      #pragma unroll
      for (int h = 0; h < 3; ++h){
        ushort4 pk;
        pk.x = f2bf(acc[i][h*4+0]); pk.y = f2bf(acc[i][h*4+1]);
        pk.z = f2bf(acc[i][h*4+2]); pk.w = f2bf(acc[i][h*4+3]);
        *reinterpret_cast<ushort4*>(xw + (size_t)gr*192 + h*64 + c0) = pk;
      }
      if (g == 0){
        #pragma unroll
        for (int h = 0; h < 3; ++h){ asrc[gr*3+h] = ps[h]; adst[gr*3+h] = pd[h]; }
      }
    }
  }
}

// per-node online-softmax attention aggregation: one wave per node
__global__ __launch_bounds__(256) void k_agg(
    const int* __restrict__ row_ptr, const int* __restrict__ src_s,
    const float* __restrict__ el_s,
    const float* __restrict__ asrc, const float* __restrict__ adst,
    const unsigned short* __restrict__ xw,
    const float* __restrict__ bg,
    float* __restrict__ mbuf)
{
  int n = blockIdx.x*4 + (threadIdx.x >> 6);
  int c = threadIdx.x & 63;
  if (n >= N_) return;
  int p0 = row_ptr[n], p1 = row_ptr[n+1];
  float ad0 = adst[n*3+0], ad1 = adst[n*3+1], ad2 = adst[n*3+2];
  float m0 = -3.0e38f, m1 = -3.0e38f, m2 = -3.0e38f;
  float d0 = 0.f, d1 = 0.f, d2 = 0.f;
  float a0 = 0.f, a1 = 0.f, a2 = 0.f;
  for (int p = p0; p < p1; ++p){
    int s = src_s[p];
    float l0 = asrc[s*3+0] + ad0 + el_s[p*3+0];
    float l1 = asrc[s*3+1] + ad1 + el_s[p*3+1];
    float l2 = asrc[s*3+2] + ad2 + el_s[p*3+2];
    l0 = l0 > 0.f ? l0 : 0.2f*l0;
    l1 = l1 > 0.f ? l1 : 0.2f*l1;
    l2 = l2 > 0.f ? l2 : 0.2f*l2;
    const unsigned short* xp = xw + (size_t)s*192 + c;
    float v0 = bf2f(xp[0]), v1 = bf2f(xp[64]), v2 = bf2f(xp[128]);
    float nm, f, w;
    nm = fmaxf(m0,l0); f = __expf(m0-nm); w = __expf(l0-nm);
    d0 = d0*f + w; a0 = a0*f + w*v0; m0 = nm;
    nm = fmaxf(m1,l1); f = __expf(m1-nm); w = __expf(l1-nm);
    d1 = d1*f + w; a1 = a1*f + w*v1; m1 = nm;
    nm = fmaxf(m2,l2); f = __expf(m2-nm); w = __expf(l2-nm);
    d2 = d2*f + w; a2 = a2*f + w*v2; m2 = nm;
  }
  float mp = (a0/(d0+1e-16f) + a1/(d1+1e-16f) + a2/(d2+1e-16f)) * (1.0f/3.0f) + bg[c];
  mbuf[(size_t)n*64 + c] = mp > 0.f ? mp : (__expf(mp) - 1.0f);  // celu
}

// GRU step: gi = m@Wih^T+bih, gh = h@Whh^T+bhh, gates, h update; BN stats
__global__ __launch_bounds__(256) void k_gru(
    const float* __restrict__ mbuf, float* __restrict__ hbuf,
    const float* __restrict__ WihT, const float* __restrict__ WhhT,
    const float* __restrict__ bih, const float* __restrict__ bhh,
    float* __restrict__ bn_stats)
{
  __shared__ float sM[64][65];
  __shared__ float sH[64][65];
  __shared__ float sStat[128];
  const int t = threadIdx.x;
  const int row0 = blockIdx.x * 64;
  if (t < 128) sStat[t] = 0.f;
  {
    int lr = t >> 4, k4 = (t & 15) * 4;
    #pragma unroll
    for (int i = 0; i < 4; ++i){
      int r = lr + i*16, gr = row0 + r;
      float4 vm = make_float4(0.f,0.f,0.f,0.f), vh = vm;
      if (gr < N_){ vm = ldg4(mbuf + (size_t)gr*64 + k4); vh = ldg4(hbuf + (size_t)gr*64 + k4); }
      sM[r][k4+0]=vm.x; sM[r][k4+1]=vm.y; sM[r][k4+2]=vm.z; sM[r][k4+3]=vm.w;
      sH[r][k4+0]=vh.x; sH[r][k4+1]=vh.y; sH[r][k4+2]=vh.z; sH[r][k4+3]=vh.w;
    }
  }
  __syncthreads();
  const int g = t & 15, rq = t >> 4, c0 = g * 4;
  float ai[4][12], ah[4][12];
  for (int i = 0; i < 4; ++i)
    for (int j = 0; j < 12; ++j){ ai[i][j] = 0.f; ah[i][j] = 0.f; }
  #pragma unroll 2
  for (int k = 0; k < 64; ++k){
    const float* wi = WihT + k*192;
    const float* wh = WhhT + k*192;
    float4 wi0 = ldg4(wi + c0), wi1 = ldg4(wi + 64 + c0), wi2 = ldg4(wi + 128 + c0);
    float4 wh0 = ldg4(wh + c0), wh1 = ldg4(wh + 64 + c0), wh2 = ldg4(wh + 128 + c0);
    float wiv[12] = {wi0.x,wi0.y,wi0.z,wi0.w, wi1.x,wi1.y,wi1.z,wi1.w, wi2.x,wi2.y,wi2.z,wi2.w};
    float whv[12] = {wh0.x,wh0.y,wh0.z,wh0.w, wh1.x,wh1.y,wh1.z,wh1.w, wh2.x,wh2.y,wh2.z,wh2.w};
    #pragma unroll
    for (int i = 0; i < 4; ++i){
      float mv = sM[rq*4+i][k], hv = sH[rq*4+i][k];
      #pragma unroll
      for (int j = 0; j < 12; ++j){
        ai[i][j] = fmaf(mv, wiv[j], ai[i][j]);
        ah[i][j] = fmaf(hv, whv[j], ah[i][j]);
      }
    }
  }
  float4 bi0 = ldg4(bih + c0), bi1 = ldg4(bih + 64 + c0), bi2 = ldg4(bih + 128 + c0);
  float4 bh0 = ldg4(bhh + c0), bh1 = ldg4(bhh + 64 + c0), bh2 = ldg4(bhh + 128 + c0);
  float biv[12] = {bi0.x,bi0.y,bi0.z,bi0.w, bi1.x,bi1.y,bi1.z,bi1.w, bi2.x,bi2.y,bi2.z,bi2.w};
  float bhv[12] = {bh0.x,bh0.y,bh0.z,bh0.w, bh1.x,bh1.y,bh1.z,bh1.w, bh2.x,bh2.y,bh2.z,bh2.w};
  float s1[4] = {0.f,0.f,0.f,0.f}, s2[4] = {0.f,0.f,0.f,0.f};
  #pragma unroll
  for (int i = 0; i < 4; ++i){
    int r = rq*4 + i, gr = row0 + r;
    float hnew[4];
    #pragma unroll
    for (int cc = 0; cc < 4; ++cc){
      float ir = ai[i][cc]   + biv[cc],   hr = ah[i][cc]   + bhv[cc];
      float iz = ai[i][4+cc] + biv[4+cc], hz = ah[i][4+cc] + bhv[4+cc];
      float in_= ai[i][8+cc] + biv[8+cc], hn = ah[i][8+cc] + bhv[8+cc];
      float rg = sigmoidf_(ir + hr);
      float zg = sigmoidf_(iz + hz);
      float ng = tanhf(in_ + rg*hn);
      float ho = sH[r][c0+cc];
      float hv = (1.f - zg)*ng + zg*ho;
      hnew[cc] = hv;
      if (gr < N_){ s1[cc] += hv; s2[cc] += hv*hv; }
    }
    if (gr < N_){
      float4 o; o.x=hnew[0]; o.y=hnew[1]; o.z=hnew[2]; o.w=hnew[3];
      *reinterpret_cast<float4*>(hbuf + (size_t)gr*64 + c0) = o;
    }
  }
  #pragma unroll
  for (int cc = 0; cc < 4; ++cc){
    float v = s1[cc];
    v += __shfl_xor(v, 16); v += __shfl_xor(v, 32);
    float w = s2[cc];
    w += __shfl_xor(w, 16); w += __shfl_xor(w, 32);
    if ((t & 63) < 16){
      atomicAdd(&sStat[c0+cc], v);
      atomicAdd(&sStat[64+c0+cc], w);
    }
  }
  __syncthreads();
  if (t < 128) atomicAdd(&bn_stats[t], sStat[t]);
}

__global__ void k_bnfin(const float* __restrict__ bn_stats,
                        const float* __restrict__ gamma, const float* __restrict__ beta,
                        int step, float* __restrict__ coef){
  int c = threadIdx.x; if (c >= 64) return;
  float mu  = bn_stats[c] * (1.0f/30000.0f);
  float var = bn_stats[64+c] * (1.0f/30000.0f) - mu*mu;
  float rs = rsqrtf(var + 1e-5f);
  float sc = gamma[step*64 + c] * rs;
  coef[c] = sc;
  coef[64+c] = beta[step*64 + c] - mu*sc;
}

__global__ void k_bnapply(const float* __restrict__ hbuf, const float* __restrict__ coef,
                          float* __restrict__ feats, int slot){
  int idx = blockIdx.x*256 + threadIdx.x;
  int n = idx >> 4, c4 = (idx & 15) * 4;
  if (n >= N_) return;
  float4 h4 = ldg4(hbuf + (size_t)n*64 + c4);
  float4 sc = ldg4(coef + c4);
  float4 sh = ldg4(coef + 64 + c4);
  float4 o;
  o.x = fmaf(h4.x, sc.x, sh.x); o.y = fmaf(h4.y, sc.y, sh.y);
  o.z = fmaf(h4.z, sc.z, sh.z); o.w = fmaf(h4.w, sc.w, sh.w);
  *reinterpret_cast<float4*>(feats + (size_t)n*448 + slot*64 + c4) = o;
}

// out = feats[30000,448] @ Wlin[448,64] + blin
__global__ __launch_bounds__(256) void k_final(
    const float* __restrict__ feats, const float* __restrict__ Wlin,
    const float* __restrict__ blin, float* __restrict__ out)
{
  __shared__ float sF[64][65];
  const int t = threadIdx.x;
  const int row0 = blockIdx.x * 64;
  const int g = t & 15, rq = t >> 4, c0 = g * 4;
  float acc[4][4];
  for (int i = 0; i < 4; ++i)
    for (int j = 0; j < 4; ++j) acc[i][j] = 0.f;
  for (int kc = 0; kc < 7; ++kc){
    __syncthreads();
    {
      int lr = t >> 4, k4 = (t & 15) * 4;
      #pragma unroll
      for (int i = 0; i < 4; ++i){
        int r = lr + i*16, gr = row0 + r;
        float4 v = make_float4(0.f,0.f,0.f,0.f);
        if (gr < N_) v = ldg4(feats + (size_t)gr*448 + kc*64 + k4);
        sF[r][k4+0]=v.x; sF[r][k4+1]=v.y; sF[r][k4+2]=v.z; sF[r][k4+3]=v.w;
      }
    }
    __syncthreads();
    #pragma unroll 4
    for (int k = 0; k < 64; ++k){
      float4 w = ldg4(Wlin + (size_t)(kc*64 + k)*64 + c0);
      #pragma unroll
      for (int i = 0; i < 4; ++i){
        float xv = sF[rq*4+i][k];
        acc[i][0] = fmaf(xv, w.x, acc[i][0]);
        acc[i][1] = fmaf(xv, w.y, acc[i][1]);
        acc[i][2] = fmaf(xv, w.z, acc[i][2]);
        acc[i][3] = fmaf(xv, w.w, acc[i][3]);
      }
    }
  }
  float4 b = ldg4(blin + c0);
  #pragma unroll
  for (int i = 0; i < 4; ++i){
    int gr = row0 + rq*4 + i;
    if (gr < N_){
      float4 o;
      o.x = acc[i][0]+b.x; o.y = acc[i][1]+b.y; o.z = acc[i][2]+b.z; o.w = acc[i][3]+b.w;
      *reinterpret_cast<float4*>(out + (size_t)gr*64 + c0) = o;
    }
  }
}

// ---------------- launch ----------------

extern "C" void kernel_launch(void* const* d_in, const int* in_sizes, int n_in,
                              void* d_out, int out_size, void* d_ws, size_t ws_size,
                              hipStream_t stream) {
  const float* x        = (const float*)d_in[0];
  const int*   ei       = (const int*)  d_in[1];
  const float* edge_attr= (const float*)d_in[2];
  const float* Wg       = (const float*)d_in[3];
  const float* bg       = (const float*)d_in[4];
  const float* a_src    = (const float*)d_in[5];
  const float* a_dst    = (const float*)d_in[6];
  const float* We       = (const float*)d_in[7];
  const float* a_edge   = (const float*)d_in[8];
  const float* Wih      = (const float*)d_in[9];
  const float* Whh      = (const float*)d_in[10];
  const float* bih      = (const float*)d_in[11];
  const float* bhh      = (const float*)d_in[12];
  const float* gamma    = (const float*)d_in[13];
  const float* beta     = (const float*)d_in[14];
  const float* Wlin     = (const float*)d_in[15];
  const float* blin     = (const float*)d_in[16];
  float* out = (float*)d_out;

  char* w = (char*)d_ws;
  auto alloc = [&](size_t bytes) -> void* {
    void* p = (void*)w;
    w += (bytes + 255) & ~(size_t)255;
    return p;
  };
  int*   row_ptr = (int*)  alloc((size_t)(N_+1)*4);
  int*   cursor  = (int*)  alloc((size_t)N_*4);
  int*   src_s   = (int*)  alloc((size_t)E_*4);
  float* el      = (float*)alloc((size_t)E_*3*4);
  float* el_s    = (float*)alloc((size_t)E_*3*4);
  float* Pw      = (float*)alloc(48*4);
  float* WihT    = (float*)alloc(192*64*4);
  float* WhhT    = (float*)alloc(192*64*4);
  unsigned short* xw = (unsigned short*)alloc((size_t)N_*192*2);
  float* asrc    = (float*)alloc((size_t)N_*3*4);
  float* adst    = (float*)alloc((size_t)N_*3*4);
  float* mbuf    = (float*)alloc((size_t)N_*64*4);
  float* hbuf    = (float*)alloc((size_t)N_*64*4);
  float* feats   = (float*)alloc((size_t)N_*448*4);
  float* bn_stats= (float*)alloc(128*4);
  float* coef    = (float*)alloc(128*4);

  const int EB = (E_ + 255)/256;       // 1172
  const int GEMMB = (N_ + 63)/64;      // 469
  const int VECB = (N_*16 + 255)/256;  // 1875

  k_zero   <<<(N_+1+255)/256, 256, 0, stream>>>(row_ptr);
  k_P      <<<1, 64, 0, stream>>>(We, a_edge, Pw);
  k_wt     <<<96, 256, 0, stream>>>(Wih, Whh, WihT, WhhT);
  k_el     <<<EB, 256, 0, stream>>>(edge_attr, Pw, el);
  k_hist   <<<EB, 256, 0, stream>>>(ei, row_ptr);
  k_scan   <<<1, 1024, 0, stream>>>(row_ptr, cursor);
  k_scatter<<<EB, 256, 0, stream>>>(ei, el, cursor, src_s, el_s);
  k_copy   <<<VECB, 256, 0, stream>>>(x, hbuf, feats);

  for (int step = 0; step < 6; ++step){
    k_xw     <<<GEMMB, 256, 0, stream>>>(feats + step*64, Wg, a_src, a_dst,
                                         xw, asrc, adst, bn_stats);
    k_agg    <<<(N_+3)/4, 256, 0, stream>>>(row_ptr, src_s, el_s, asrc, adst, xw, bg, mbuf);
    k_gru    <<<GEMMB, 256, 0, stream>>>(mbuf, hbuf, WihT, WhhT, bih, bhh, bn_stats);
    k_bnfin  <<<1, 64, 0, stream>>>(bn_stats, gamma, beta, step, coef);
    k_bnapply<<<VECB, 256, 0, stream>>>(hbuf, coef, feats, step + 1);
  }
  k_final<<<GEMMB, 256, 0, stream>>>(feats, Wlin, blin, out);
}

// Round 3
// 919.614 us; speedup vs baseline: 1.0878x; 1.0878x over previous
//
#include <hip/hip_runtime.h>
#include <math.h>

constexpr int N_ = 30000;
constexpr int E_ = 300000;
constexpr int SCB = (N_ + 255) / 256;   // 118 scan blocks

__device__ __forceinline__ float4 ldg4(const float* p){ return *reinterpret_cast<const float4*>(p); }

__device__ __forceinline__ unsigned short f2bf(float f){
  union { float f; unsigned int u; } v; v.f = f;
  unsigned int r = v.u + 0x7FFFu + ((v.u >> 16) & 1u);
  return (unsigned short)(r >> 16);
}
__device__ __forceinline__ float bf2f(unsigned short b){
  union { unsigned int u; float f; } v; v.u = ((unsigned int)b) << 16;
  return v.f;
}
__device__ __forceinline__ float sigmoidf_(float x){ return 1.0f/(1.0f + __expf(-x)); }

// ---------------- setup kernels (once per launch) ----------------

__global__ void k_zero(int* __restrict__ deg){
  int i = blockIdx.x*256 + threadIdx.x;
  if (i < N_) deg[i] = 0;
}

// blocks 0..95: transpose Wih/Whh; block 96: P[j][h] = sum_c We[j,h*64+c]*a_edge[h,c]
__global__ void k_wtP(const float* __restrict__ Wih, const float* __restrict__ Whh,
                      const float* __restrict__ We, const float* __restrict__ a_edge,
                      float* __restrict__ WihT, float* __restrict__ WhhT,
                      float* __restrict__ P){
  if (blockIdx.x == 96){
    int t = threadIdx.x; if (t >= 48) return;
    int j = t / 3, h = t % 3;
    float s = 0.f;
    for (int c = 0; c < 64; ++c) s += We[j*192 + h*64 + c] * a_edge[h*64 + c];
    P[j*3 + h] = s;
    return;
  }
  int idx = blockIdx.x*256 + threadIdx.x;
  if (idx < 12288){ int k = idx / 192, col = idx % 192; WihT[idx] = Wih[col*64 + k]; }
  else if (idx < 24576){
    int r = idx - 12288; int k = r / 192, col = r % 192; WhhT[r] = Whh[col*64 + k];
  }
}

__global__ void k_hist(const int* __restrict__ ei, int* __restrict__ deg){
  int e = blockIdx.x*256 + threadIdx.x;
  if (e < E_) atomicAdd(&deg[ei[E_ + e]], 1);
}

__global__ void k_scanA(const int* __restrict__ deg, int* __restrict__ partial){
  int i = blockIdx.x*256 + threadIdx.x;
  int v = (i < N_) ? deg[i] : 0;
  #pragma unroll
  for (int off = 1; off < 64; off <<= 1) v += __shfl_xor(v, off);
  __shared__ int ws[4];
  if ((threadIdx.x & 63) == 0) ws[threadIdx.x >> 6] = v;
  __syncthreads();
  if (threadIdx.x == 0) partial[blockIdx.x] = ws[0] + ws[1] + ws[2] + ws[3];
}

__global__ void k_scanB(int* __restrict__ partial, int* __restrict__ row_ptr){
  __shared__ int s[128];
  int t = threadIdx.x;
  int v = (t < SCB) ? partial[t] : 0;
  s[t] = v; __syncthreads();
  for (int off = 1; off < 128; off <<= 1){
    int u = (t >= off) ? s[t-off] : 0;
    __syncthreads();
    s[t] += u;
    __syncthreads();
  }
  if (t < SCB) partial[t] = s[t] - v;   // exclusive
  if (t == 0) row_ptr[N_] = E_;
}

__global__ void k_scanC(const int* __restrict__ deg, const int* __restrict__ partial,
                        int* __restrict__ row_ptr, int* __restrict__ cursor){
  __shared__ int s[256];
  int t = threadIdx.x, i = blockIdx.x*256 + t;
  int v = (i < N_) ? deg[i] : 0;
  s[t] = v; __syncthreads();
  for (int off = 1; off < 256; off <<= 1){
    int u = (t >= off) ? s[t-off] : 0;
    __syncthreads();
    s[t] += u;
    __syncthreads();
  }
  int ex = s[t] - v + partial[blockIdx.x];
  if (i < N_){ row_ptr[i] = ex; cursor[i] = ex; }
}

// fused: edge logits (edge_attr @ P) + CSR scatter
__global__ void k_scatter(const int* __restrict__ ei, const float* __restrict__ edge_attr,
                          const float* __restrict__ P,
                          int* __restrict__ cursor, int* __restrict__ src_s,
                          float* __restrict__ el_s){
  __shared__ float sP[48];
  int t = threadIdx.x;
  if (t < 48) sP[t] = P[t];
  __syncthreads();
  int e = blockIdx.x*256 + t;
  if (e >= E_) return;
  const float* ea = edge_attr + (size_t)e*16;
  float v[16];
  #pragma unroll
  for (int q = 0; q < 4; ++q){
    float4 f = ldg4(ea + q*4);
    v[q*4+0]=f.x; v[q*4+1]=f.y; v[q*4+2]=f.z; v[q*4+3]=f.w;
  }
  float l0=0.f,l1=0.f,l2=0.f;
  #pragma unroll
  for (int j = 0; j < 16; ++j){
    l0 += v[j]*sP[j*3+0]; l1 += v[j]*sP[j*3+1]; l2 += v[j]*sP[j*3+2];
  }
  int d = ei[E_ + e];
  int p = atomicAdd(&cursor[d], 1);
  src_s[p] = ei[e];
  el_s[p*3+0] = l0; el_s[p*3+1] = l1; el_s[p*3+2] = l2;
}

// ---------------- per-step kernels ----------------

// fused BN(hsrc) -> feats slot + xw GEMM (bf16 out) + alpha_src/dst dots
// bn==0: hsrc is raw x (identity coef). gidx = gamma/beta row (step-1).
__global__ __launch_bounds__(256) void k_xw(
    const float* __restrict__ hsrc,                // stride 64
    const float* __restrict__ bn_stats,
    const float* __restrict__ gamma, const float* __restrict__ beta,
    int gidx, int bn, int slot,
    const float* __restrict__ Wg,
    const float* __restrict__ a_src, const float* __restrict__ a_dst,
    unsigned short* __restrict__ xw,
    float* __restrict__ asrc, float* __restrict__ adst,
    float* __restrict__ feats)
{
  __shared__ float sX[64][65];
  __shared__ float sSc[64], sSh[64];
  const int t = threadIdx.x;
  const int row0 = blockIdx.x * 64;
  if (t < 64){
    float sc = 1.f, sh = 0.f;
    if (bn){
      float mu  = bn_stats[t] * (1.0f/30000.0f);
      float var = bn_stats[64+t] * (1.0f/30000.0f) - mu*mu;
      float rs = rsqrtf(var + 1e-5f);
      sc = gamma[gidx*64 + t] * rs;
      sh = beta[gidx*64 + t] - mu*sc;
    }
    sSc[t] = sc; sSh[t] = sh;
  }
  __syncthreads();
  {
    int lr = t >> 4, k4 = (t & 15) * 4;
    float sc0=sSc[k4],sc1=sSc[k4+1],sc2=sSc[k4+2],sc3=sSc[k4+3];
    float sh0=sSh[k4],sh1=sSh[k4+1],sh2=sSh[k4+2],sh3=sSh[k4+3];
    #pragma unroll
    for (int i = 0; i < 4; ++i){
      int r = lr + i*16, gr = row0 + r;
      float4 v = make_float4(0.f,0.f,0.f,0.f);
      if (gr < N_){
        v = ldg4(hsrc + (size_t)gr*64 + k4);
        v.x = fmaf(v.x, sc0, sh0); v.y = fmaf(v.y, sc1, sh1);
        v.z = fmaf(v.z, sc2, sh2); v.w = fmaf(v.w, sc3, sh3);
        *reinterpret_cast<float4*>(feats + (size_t)gr*448 + slot*64 + k4) = v;
      }
      sX[r][k4+0]=v.x; sX[r][k4+1]=v.y; sX[r][k4+2]=v.z; sX[r][k4+3]=v.w;
    }
  }
  __syncthreads();
  const int g = t & 15, rq = t >> 4, c0 = g * 4;
  float acc[4][12];
  for (int i = 0; i < 4; ++i)
    for (int j = 0; j < 12; ++j) acc[i][j] = 0.f;
  #pragma unroll 4
  for (int k = 0; k < 64; ++k){
    const float* wp = Wg + k*192;
    float4 w0 = ldg4(wp + c0), w1 = ldg4(wp + 64 + c0), w2 = ldg4(wp + 128 + c0);
    float wv[12] = {w0.x,w0.y,w0.z,w0.w, w1.x,w1.y,w1.z,w1.w, w2.x,w2.y,w2.z,w2.w};
    #pragma unroll
    for (int i = 0; i < 4; ++i){
      float xv = sX[rq*4+i][k];
      #pragma unroll
      for (int j = 0; j < 12; ++j) acc[i][j] = fmaf(xv, wv[j], acc[i][j]);
    }
  }
  float asw[12], adw[12];
  #pragma unroll
  for (int h = 0; h < 3; ++h){
    float4 a1 = ldg4(a_src + h*64 + c0), a2 = ldg4(a_dst + h*64 + c0);
    asw[h*4+0]=a1.x; asw[h*4+1]=a1.y; asw[h*4+2]=a1.z; asw[h*4+3]=a1.w;
    adw[h*4+0]=a2.x; adw[h*4+1]=a2.y; adw[h*4+2]=a2.z; adw[h*4+3]=a2.w;
  }
  #pragma unroll
  for (int i = 0; i < 4; ++i){
    int gr = row0 + rq*4 + i;
    float ps[3], pd[3];
    #pragma unroll
    for (int h = 0; h < 3; ++h){
      float s = 0.f, d = 0.f;
      #pragma unroll
      for (int cc = 0; cc < 4; ++cc){
        s = fmaf(acc[i][h*4+cc], asw[h*4+cc], s);
        d = fmaf(acc[i][h*4+cc], adw[h*4+cc], d);
      }
      s += __shfl_xor(s,1); s += __shfl_xor(s,2); s += __shfl_xor(s,4); s += __shfl_xor(s,8);
      d += __shfl_xor(d,1); d += __shfl_xor(d,2); d += __shfl_xor(d,4); d += __shfl_xor(d,8);
      ps[h] = s; pd[h] = d;
    }
    if (gr < N_){
      #pragma unroll
      for (int h = 0; h < 3; ++h){
        ushort4 pk;
        pk.x = f2bf(acc[i][h*4+0]); pk.y = f2bf(acc[i][h*4+1]);
        pk.z = f2bf(acc[i][h*4+2]); pk.w = f2bf(acc[i][h*4+3]);
        *reinterpret_cast<ushort4*>(xw + (size_t)gr*192 + h*64 + c0) = pk;
      }
      if (g == 0){
        #pragma unroll
        for (int h = 0; h < 3; ++h){ asrc[gr*3+h] = ps[h]; adst[gr*3+h] = pd[h]; }
      }
    }
  }
}

// per-node online-softmax attention aggregation: one wave per node.
// block 0 also zeroes bn_stats for the following k_gru (stream-ordered: k_xw
// that READS bn_stats completed before this kernel starts).
__global__ __launch_bounds__(256) void k_agg(
    const int* __restrict__ row_ptr, const int* __restrict__ src_s,
    const float* __restrict__ el_s,
    const float* __restrict__ asrc, const float* __restrict__ adst,
    const unsigned short* __restrict__ xw,
    const float* __restrict__ bg,
    float* __restrict__ mbuf, float* __restrict__ bn_stats)
{
  if (blockIdx.x == 0 && threadIdx.x < 128) bn_stats[threadIdx.x] = 0.f;
  int n = blockIdx.x*4 + (threadIdx.x >> 6);
  int c = threadIdx.x & 63;
  if (n >= N_) return;
  int p0 = row_ptr[n], p1 = row_ptr[n+1];
  float ad0 = adst[n*3+0], ad1 = adst[n*3+1], ad2 = adst[n*3+2];
  float m0 = -3.0e38f, m1 = -3.0e38f, m2 = -3.0e38f;
  float d0 = 0.f, d1 = 0.f, d2 = 0.f;
  float a0 = 0.f, a1 = 0.f, a2 = 0.f;
  for (int p = p0; p < p1; ++p){
    int s = src_s[p];
    float l0 = asrc[s*3+0] + ad0 + el_s[p*3+0];
    float l1 = asrc[s*3+1] + ad1 + el_s[p*3+1];
    float l2 = asrc[s*3+2] + ad2 + el_s[p*3+2];
    l0 = l0 > 0.f ? l0 : 0.2f*l0;
    l1 = l1 > 0.f ? l1 : 0.2f*l1;
    l2 = l2 > 0.f ? l2 : 0.2f*l2;
    const unsigned short* xp = xw + (size_t)s*192 + c;
    float v0 = bf2f(xp[0]), v1 = bf2f(xp[64]), v2 = bf2f(xp[128]);
    float nm, f, w;
    nm = fmaxf(m0,l0); f = __expf(m0-nm); w = __expf(l0-nm);
    d0 = d0*f + w; a0 = a0*f + w*v0; m0 = nm;
    nm = fmaxf(m1,l1); f = __expf(m1-nm); w = __expf(l1-nm);
    d1 = d1*f + w; a1 = a1*f + w*v1; m1 = nm;
    nm = fmaxf(m2,l2); f = __expf(m2-nm); w = __expf(l2-nm);
    d2 = d2*f + w; a2 = a2*f + w*v2; m2 = nm;
  }
  float mp = (a0/(d0+1e-16f) + a1/(d1+1e-16f) + a2/(d2+1e-16f)) * (1.0f/3.0f) + bg[c];
  mbuf[(size_t)n*64 + c] = mp > 0.f ? mp : (__expf(mp) - 1.0f);  // celu
}

// GRU step; hsrc = x (step 0) or hbuf. Writes hbuf + bn_stats.
__global__ __launch_bounds__(256) void k_gru(
    const float* __restrict__ mbuf, const float* __restrict__ hsrc,
    float* __restrict__ hbuf,
    const float* __restrict__ WihT, const float* __restrict__ WhhT,
    const float* __restrict__ bih, const float* __restrict__ bhh,
    float* __restrict__ bn_stats)
{
  __shared__ float sM[64][65];
  __shared__ float sH[64][65];
  __shared__ float sStat[128];
  const int t = threadIdx.x;
  const int row0 = blockIdx.x * 64;
  if (t < 128) sStat[t] = 0.f;
  {
    int lr = t >> 4, k4 = (t & 15) * 4;
    #pragma unroll
    for (int i = 0; i < 4; ++i){
      int r = lr + i*16, gr = row0 + r;
      float4 vm = make_float4(0.f,0.f,0.f,0.f), vh = vm;
      if (gr < N_){ vm = ldg4(mbuf + (size_t)gr*64 + k4); vh = ldg4(hsrc + (size_t)gr*64 + k4); }
      sM[r][k4+0]=vm.x; sM[r][k4+1]=vm.y; sM[r][k4+2]=vm.z; sM[r][k4+3]=vm.w;
      sH[r][k4+0]=vh.x; sH[r][k4+1]=vh.y; sH[r][k4+2]=vh.z; sH[r][k4+3]=vh.w;
    }
  }
  __syncthreads();
  const int g = t & 15, rq = t >> 4, c0 = g * 4;
  float ai[4][12], ah[4][12];
  for (int i = 0; i < 4; ++i)
    for (int j = 0; j < 12; ++j){ ai[i][j] = 0.f; ah[i][j] = 0.f; }
  #pragma unroll 2
  for (int k = 0; k < 64; ++k){
    const float* wi = WihT + k*192;
    const float* wh = WhhT + k*192;
    float4 wi0 = ldg4(wi + c0), wi1 = ldg4(wi + 64 + c0), wi2 = ldg4(wi + 128 + c0);
    float4 wh0 = ldg4(wh + c0), wh1 = ldg4(wh + 64 + c0), wh2 = ldg4(wh + 128 + c0);
    float wiv[12] = {wi0.x,wi0.y,wi0.z,wi0.w, wi1.x,wi1.y,wi1.z,wi1.w, wi2.x,wi2.y,wi2.z,wi2.w};
    float whv[12] = {wh0.x,wh0.y,wh0.z,wh0.w, wh1.x,wh1.y,wh1.z,wh1.w, wh2.x,wh2.y,wh2.z,wh2.w};
    #pragma unroll
    for (int i = 0; i < 4; ++i){
      float mv = sM[rq*4+i][k], hv = sH[rq*4+i][k];
      #pragma unroll
      for (int j = 0; j < 12; ++j){
        ai[i][j] = fmaf(mv, wiv[j], ai[i][j]);
        ah[i][j] = fmaf(hv, whv[j], ah[i][j]);
      }
    }
  }
  float4 bi0 = ldg4(bih + c0), bi1 = ldg4(bih + 64 + c0), bi2 = ldg4(bih + 128 + c0);
  float4 bh0 = ldg4(bhh + c0), bh1 = ldg4(bhh + 64 + c0), bh2 = ldg4(bhh + 128 + c0);
  float biv[12] = {bi0.x,bi0.y,bi0.z,bi0.w, bi1.x,bi1.y,bi1.z,bi1.w, bi2.x,bi2.y,bi2.z,bi2.w};
  float bhv[12] = {bh0.x,bh0.y,bh0.z,bh0.w, bh1.x,bh1.y,bh1.z,bh1.w, bh2.x,bh2.y,bh2.z,bh2.w};
  float s1[4] = {0.f,0.f,0.f,0.f}, s2[4] = {0.f,0.f,0.f,0.f};
  #pragma unroll
  for (int i = 0; i < 4; ++i){
    int r = rq*4 + i, gr = row0 + r;
    float hnew[4];
    #pragma unroll
    for (int cc = 0; cc < 4; ++cc){
      float ir = ai[i][cc]   + biv[cc],   hr = ah[i][cc]   + bhv[cc];
      float iz = ai[i][4+cc] + biv[4+cc], hz = ah[i][4+cc] + bhv[4+cc];
      float in_= ai[i][8+cc] + biv[8+cc], hn = ah[i][8+cc] + bhv[8+cc];
      float rg = sigmoidf_(ir + hr);
      float zg = sigmoidf_(iz + hz);
      float ng = tanhf(in_ + rg*hn);
      float ho = sH[r][c0+cc];
      float hv = (1.f - zg)*ng + zg*ho;
      hnew[cc] = hv;
      if (gr < N_){ s1[cc] += hv; s2[cc] += hv*hv; }
    }
    if (gr < N_){
      float4 o; o.x=hnew[0]; o.y=hnew[1]; o.z=hnew[2]; o.w=hnew[3];
      *reinterpret_cast<float4*>(hbuf + (size_t)gr*64 + c0) = o;
    }
  }
  #pragma unroll
  for (int cc = 0; cc < 4; ++cc){
    float v = s1[cc];
    v += __shfl_xor(v, 16); v += __shfl_xor(v, 32);
    float w = s2[cc];
    w += __shfl_xor(w, 16); w += __shfl_xor(w, 32);
    if ((t & 63) < 16){
      atomicAdd(&sStat[c0+cc], v);
      atomicAdd(&sStat[64+c0+cc], w);
    }
  }
  __syncthreads();
  if (t < 128) atomicAdd(&bn_stats[t], sStat[t]);
}

// out = [feats(0..5) | bn(hbuf)] @ Wlin + blin ; BN coef from bn_stats inline
__global__ __launch_bounds__(256) void k_final(
    const float* __restrict__ feats, const float* __restrict__ hbuf,
    const float* __restrict__ bn_stats,
    const float* __restrict__ gamma, const float* __restrict__ beta,
    const float* __restrict__ Wlin, const float* __restrict__ blin,
    float* __restrict__ out)
{
  __shared__ float sF[64][65];
  __shared__ float sSc[64], sSh[64];
  const int t = threadIdx.x;
  const int row0 = blockIdx.x * 64;
  if (t < 64){
    float mu  = bn_stats[t] * (1.0f/30000.0f);
    float var = bn_stats[64+t] * (1.0f/30000.0f) - mu*mu;
    float rs = rsqrtf(var + 1e-5f);
    float sc = gamma[5*64 + t] * rs;
    sSc[t] = sc;
    sSh[t] = beta[5*64 + t] - mu*sc;
  }
  const int g = t & 15, rq = t >> 4, c0 = g * 4;
  float acc[4][4];
  for (int i = 0; i < 4; ++i)
    for (int j = 0; j < 4; ++j) acc[i][j] = 0.f;
  for (int kc = 0; kc < 7; ++kc){
    __syncthreads();
    {
      int lr = t >> 4, k4 = (t & 15) * 4;
      #pragma unroll
      for (int i = 0; i < 4; ++i){
        int r = lr + i*16, gr = row0 + r;
        float4 v = make_float4(0.f,0.f,0.f,0.f);
        if (gr < N_){
          if (kc < 6) v = ldg4(feats + (size_t)gr*448 + kc*64 + k4);
          else {
            v = ldg4(hbuf + (size_t)gr*64 + k4);
            v.x = fmaf(v.x, sSc[k4+0], sSh[k4+0]);
            v.y = fmaf(v.y, sSc[k4+1], sSh[k4+1]);
            v.z = fmaf(v.z, sSc[k4+2], sSh[k4+2]);
            v.w = fmaf(v.w, sSc[k4+3], sSh[k4+3]);
          }
        }
        sF[r][k4+0]=v.x; sF[r][k4+1]=v.y; sF[r][k4+2]=v.z; sF[r][k4+3]=v.w;
      }
    }
    __syncthreads();
    #pragma unroll 4
    for (int k = 0; k < 64; ++k){
      float4 w = ldg4(Wlin + (size_t)(kc*64 + k)*64 + c0);
      #pragma unroll
      for (int i = 0; i < 4; ++i){
        float xv = sF[rq*4+i][k];
        acc[i][0] = fmaf(xv, w.x, acc[i][0]);
        acc[i][1] = fmaf(xv, w.y, acc[i][1]);
        acc[i][2] = fmaf(xv, w.z, acc[i][2]);
        acc[i][3] = fmaf(xv, w.w, acc[i][3]);
      }
    }
  }
  float4 b = ldg4(blin + c0);
  #pragma unroll
  for (int i = 0; i < 4; ++i){
    int gr = row0 + rq*4 + i;
    if (gr < N_){
      float4 o;
      o.x = acc[i][0]+b.x; o.y = acc[i][1]+b.y; o.z = acc[i][2]+b.z; o.w = acc[i][3]+b.w;
      *reinterpret_cast<float4*>(out + (size_t)gr*64 + c0) = o;
    }
  }
}

// ---------------- launch ----------------

extern "C" void kernel_launch(void* const* d_in, const int* in_sizes, int n_in,
                              void* d_out, int out_size, void* d_ws, size_t ws_size,
                              hipStream_t stream) {
  const float* x        = (const float*)d_in[0];
  const int*   ei       = (const int*)  d_in[1];
  const float* edge_attr= (const float*)d_in[2];
  const float* Wg       = (const float*)d_in[3];
  const float* bg       = (const float*)d_in[4];
  const float* a_src    = (const float*)d_in[5];
  const float* a_dst    = (const float*)d_in[6];
  const float* We       = (const float*)d_in[7];
  const float* a_edge   = (const float*)d_in[8];
  const float* Wih      = (const float*)d_in[9];
  const float* Whh      = (const float*)d_in[10];
  const float* bih      = (const float*)d_in[11];
  const float* bhh      = (const float*)d_in[12];
  const float* gamma    = (const float*)d_in[13];
  const float* beta     = (const float*)d_in[14];
  const float* Wlin     = (const float*)d_in[15];
  const float* blin     = (const float*)d_in[16];
  float* out = (float*)d_out;

  char* w = (char*)d_ws;
  auto alloc = [&](size_t bytes) -> void* {
    void* p = (void*)w;
    w += (bytes + 255) & ~(size_t)255;
    return p;
  };
  int*   row_ptr = (int*)  alloc((size_t)(N_+1)*4);
  int*   deg     = (int*)  alloc((size_t)N_*4);
  int*   cursor  = (int*)  alloc((size_t)N_*4);
  int*   partial = (int*)  alloc(128*4);
  int*   src_s   = (int*)  alloc((size_t)E_*4);
  float* el_s    = (float*)alloc((size_t)E_*3*4);
  float* Pw      = (float*)alloc(48*4);
  float* WihT    = (float*)alloc(192*64*4);
  float* WhhT    = (float*)alloc(192*64*4);
  unsigned short* xw = (unsigned short*)alloc((size_t)N_*192*2);
  float* asrc    = (float*)alloc((size_t)N_*3*4);
  float* adst    = (float*)alloc((size_t)N_*3*4);
  float* mbuf    = (float*)alloc((size_t)N_*64*4);
  float* hbuf    = (float*)alloc((size_t)N_*64*4);
  float* feats   = (float*)alloc((size_t)N_*448*4);
  float* bn_stats= (float*)alloc(128*4);

  const int EB = (E_ + 255)/256;       // 1172
  const int GEMMB = (N_ + 63)/64;      // 469

  k_zero   <<<SCB, 256, 0, stream>>>(deg);
  k_wtP    <<<97, 256, 0, stream>>>(Wih, Whh, We, a_edge, WihT, WhhT, Pw);
  k_hist   <<<EB, 256, 0, stream>>>(ei, deg);
  k_scanA  <<<SCB, 256, 0, stream>>>(deg, partial);
  k_scanB  <<<1, 128, 0, stream>>>(partial, row_ptr);
  k_scanC  <<<SCB, 256, 0, stream>>>(deg, partial, row_ptr, cursor);
  k_scatter<<<EB, 256, 0, stream>>>(ei, edge_attr, Pw, cursor, src_s, el_s);

  for (int step = 0; step < 6; ++step){
    const float* hsrc = (step == 0) ? x : hbuf;
    k_xw <<<GEMMB, 256, 0, stream>>>(hsrc, bn_stats, gamma, beta,
                                     step-1, step > 0 ? 1 : 0, step,
                                     Wg, a_src, a_dst, xw, asrc, adst, feats);
    k_agg<<<(N_+3)/4, 256, 0, stream>>>(row_ptr, src_s, el_s, asrc, adst, xw, bg,
                                        mbuf, bn_stats);
    k_gru<<<GEMMB, 256, 0, stream>>>(mbuf, hsrc, hbuf, WihT, WhhT, bih, bhh, bn_stats);
  }
  k_final<<<GEMMB, 256, 0, stream>>>(feats, hbuf, bn_stats, gamma, beta, Wlin, blin, out);
}

// Round 4
// 668.969 us; speedup vs baseline: 1.4953x; 1.3747x over previous
//
#include <hip/hip_runtime.h>
#include <math.h>

constexpr int N_ = 30000;
constexpr int E_ = 300000;
constexpr int SCB = (N_ + 255) / 256;   // 118 scan blocks

using f32x4  = __attribute__((ext_vector_type(4))) float;
using bf16x8 = __attribute__((ext_vector_type(8))) short;

__device__ __forceinline__ float4 ldg4(const float* p){ return *reinterpret_cast<const float4*>(p); }

__device__ __forceinline__ unsigned short f2bf(float f){
  union { float f; unsigned int u; } v; v.f = f;
  unsigned int r = v.u + 0x7FFFu + ((v.u >> 16) & 1u);
  return (unsigned short)(r >> 16);
}
__device__ __forceinline__ float bf2f(unsigned short b){
  union { unsigned int u; float f; } v; v.u = ((unsigned int)b) << 16;
  return v.f;
}
__device__ __forceinline__ float sigmoidf_(float x){ return 1.0f/(1.0f + __expf(-x)); }

// ---------------- setup kernels (once per launch) ----------------

__global__ void k_zero(int* __restrict__ deg){
  int i = blockIdx.x*256 + threadIdx.x;
  if (i < N_) deg[i] = 0;
}

// Build bf16 B-fragment weights for MFMA 16x16x32:
// frag element (nt,kt,l,j) = B[k = kt*32 + (l>>4)*8 + j][n = nt*16 + (l&15)]
// fG: B=Wg[64x192]; fI: B=Wih^T (Wih[192x64]); fH: B=Whh^T; fL: B=Wlin[448x64]
// block 256: P[j][h] = sum_c We[j,h*64+c]*a_edge[h,c]
__global__ void k_wfrag(const float* __restrict__ Wg, const float* __restrict__ Wih,
                        const float* __restrict__ Whh, const float* __restrict__ Wlin,
                        const float* __restrict__ We, const float* __restrict__ a_edge,
                        unsigned short* __restrict__ fG, unsigned short* __restrict__ fI,
                        unsigned short* __restrict__ fH, unsigned short* __restrict__ fL,
                        float* __restrict__ P){
  if (blockIdx.x == 256){
    int t = threadIdx.x; if (t >= 48) return;
    int j = t / 3, h = t % 3;
    float s = 0.f;
    for (int c = 0; c < 64; ++c) s += We[j*192 + h*64 + c] * a_edge[h*64 + c];
    P[j*3 + h] = s;
    return;
  }
  int id = blockIdx.x*256 + threadIdx.x;   // 0..65535
  int lid, KT;
  const float* W; unsigned short* dst; int mode;
  if (id < 12288)      { lid = id;         KT = 2;  dst = fG; mode = 0; }
  else if (id < 24576) { lid = id - 12288; KT = 2;  dst = fI; mode = 1; }
  else if (id < 36864) { lid = id - 24576; KT = 2;  dst = fH; mode = 2; }
  else                 { lid = id - 36864; KT = 14; dst = fL; mode = 3; }
  int j = lid & 7, l = (lid >> 3) & 63, rest = lid >> 9;
  int kt = rest % KT, nt = rest / KT;
  int k = kt*32 + (l>>4)*8 + j;
  int n = nt*16 + (l&15);
  float v;
  if (mode == 0)      v = Wg[k*192 + n];
  else if (mode == 1) v = Wih[n*64 + k];
  else if (mode == 2) v = Whh[n*64 + k];
  else                v = Wlin[k*64 + n];
  dst[lid] = f2bf(v);
}

__global__ void k_hist(const int* __restrict__ ei, int* __restrict__ deg){
  int e = blockIdx.x*256 + threadIdx.x;
  if (e < E_) atomicAdd(&deg[ei[E_ + e]], 1);
}

__global__ void k_scanA(const int* __restrict__ deg, int* __restrict__ partial){
  int i = blockIdx.x*256 + threadIdx.x;
  int v = (i < N_) ? deg[i] : 0;
  #pragma unroll
  for (int off = 1; off < 64; off <<= 1) v += __shfl_xor(v, off);
  __shared__ int ws[4];
  if ((threadIdx.x & 63) == 0) ws[threadIdx.x >> 6] = v;
  __syncthreads();
  if (threadIdx.x == 0) partial[blockIdx.x] = ws[0] + ws[1] + ws[2] + ws[3];
}

__global__ void k_scanB(int* __restrict__ partial, int* __restrict__ row_ptr){
  __shared__ int s[128];
  int t = threadIdx.x;
  int v = (t < SCB) ? partial[t] : 0;
  s[t] = v; __syncthreads();
  for (int off = 1; off < 128; off <<= 1){
    int u = (t >= off) ? s[t-off] : 0;
    __syncthreads();
    s[t] += u;
    __syncthreads();
  }
  if (t < SCB) partial[t] = s[t] - v;   // exclusive
  if (t == 0) row_ptr[N_] = E_;
}

__global__ void k_scanC(const int* __restrict__ deg, const int* __restrict__ partial,
                        int* __restrict__ row_ptr, int* __restrict__ cursor){
  __shared__ int s[256];
  int t = threadIdx.x, i = blockIdx.x*256 + t;
  int v = (i < N_) ? deg[i] : 0;
  s[t] = v; __syncthreads();
  for (int off = 1; off < 256; off <<= 1){
    int u = (t >= off) ? s[t-off] : 0;
    __syncthreads();
    s[t] += u;
    __syncthreads();
  }
  int ex = s[t] - v + partial[blockIdx.x];
  if (i < N_){ row_ptr[i] = ex; cursor[i] = ex; }
}

// fused: edge logits (edge_attr @ P) + CSR scatter
__global__ void k_scatter(const int* __restrict__ ei, const float* __restrict__ edge_attr,
                          const float* __restrict__ P,
                          int* __restrict__ cursor, int* __restrict__ src_s,
                          float* __restrict__ el_s){
  __shared__ float sP[48];
  int t = threadIdx.x;
  if (t < 48) sP[t] = P[t];
  __syncthreads();
  int e = blockIdx.x*256 + t;
  if (e >= E_) return;
  const float* ea = edge_attr + (size_t)e*16;
  float v[16];
  #pragma unroll
  for (int q = 0; q < 4; ++q){
    float4 f = ldg4(ea + q*4);
    v[q*4+0]=f.x; v[q*4+1]=f.y; v[q*4+2]=f.z; v[q*4+3]=f.w;
  }
  float l0=0.f,l1=0.f,l2=0.f;
  #pragma unroll
  for (int j = 0; j < 16; ++j){
    l0 += v[j]*sP[j*3+0]; l1 += v[j]*sP[j*3+1]; l2 += v[j]*sP[j*3+2];
  }
  int d = ei[E_ + e];
  int p = atomicAdd(&cursor[d], 1);
  src_s[p] = ei[e];
  el_s[p*3+0] = l0; el_s[p*3+1] = l1; el_s[p*3+2] = l2;
}

// ---------------- per-step kernels ----------------

// Staging helper geometry (64 rows x 64 k, fp32 src stride S):
// thread t, iter i: row r = (t>>4) + i*16, k4 = (t&15)*4
// frag dest: chunk = (i*2 + (k4>>5))*64 + ( (r&15) + (((k4>>3)&3)<<4) ), elem j0 = k4&7

// fused BN(hsrc)->feats + xw = bn(x)@Wg via MFMA + alpha dots
__global__ __launch_bounds__(256) void k_xw(
    const float* __restrict__ hsrc,
    const float* __restrict__ bn_stats,
    const float* __restrict__ gamma, const float* __restrict__ beta,
    int gidx, int bn, int slot,
    const unsigned short* __restrict__ fG,
    const float* __restrict__ a_src, const float* __restrict__ a_dst,
    unsigned short* __restrict__ xw,
    float* __restrict__ asrc, float* __restrict__ adst,
    float* __restrict__ feats)
{
  __shared__ short sAf[8*64*8];        // A-frag bf16, 8 KB
  __shared__ unsigned short sXW[64*196];
  __shared__ float sSc[64], sSh[64];
  const int t = threadIdx.x;
  const int row0 = blockIdx.x * 64;
  if (t < 64){
    float sc = 1.f, sh = 0.f;
    if (bn){
      float mu  = bn_stats[t] * (1.0f/30000.0f);
      float var = bn_stats[64+t] * (1.0f/30000.0f) - mu*mu;
      float rs = rsqrtf(var + 1e-5f);
      sc = gamma[gidx*64 + t] * rs;
      sh = beta[gidx*64 + t] - mu*sc;
    }
    sSc[t] = sc; sSh[t] = sh;
  }
  __syncthreads();
  {
    const int lr = t >> 4, k4 = (t & 15) * 4;
    const float sc0=sSc[k4],sc1=sSc[k4+1],sc2=sSc[k4+2],sc3=sSc[k4+3];
    const float sh0=sSh[k4],sh1=sSh[k4+1],sh2=sSh[k4+2],sh3=sSh[k4+3];
    const int kt = k4 >> 5, lanew = lr + (((k4>>3)&3)<<4), j0 = k4 & 7;
    #pragma unroll
    for (int i = 0; i < 4; ++i){
      int r = lr + i*16, gr = row0 + r;
      float4 v = make_float4(0.f,0.f,0.f,0.f);
      if (gr < N_){
        v = ldg4(hsrc + (size_t)gr*64 + k4);
        v.x = fmaf(v.x, sc0, sh0); v.y = fmaf(v.y, sc1, sh1);
        v.z = fmaf(v.z, sc2, sh2); v.w = fmaf(v.w, sc3, sh3);
        *reinterpret_cast<float4*>(feats + (size_t)gr*448 + slot*64 + k4) = v;
      }
      ushort4 pk; pk.x=f2bf(v.x); pk.y=f2bf(v.y); pk.z=f2bf(v.z); pk.w=f2bf(v.w);
      *reinterpret_cast<ushort4*>(&sAf[((i*2+kt)*64 + lanew)*8 + j0]) = pk;
    }
  }
  __syncthreads();
  const int w = t >> 6, l = t & 63, q = l >> 4, b = l & 15;
  f32x4 acc[12];
  #pragma unroll
  for (int nt = 0; nt < 12; ++nt) acc[nt] = (f32x4){0.f,0.f,0.f,0.f};
  bf16x8 a0 = *reinterpret_cast<bf16x8*>(&sAf[((w*2+0)*64 + l)*8]);
  bf16x8 a1 = *reinterpret_cast<bf16x8*>(&sAf[((w*2+1)*64 + l)*8]);
  #pragma unroll
  for (int nt = 0; nt < 12; ++nt){
    bf16x8 b0 = *reinterpret_cast<const bf16x8*>(fG + (size_t)((nt*2+0)*64 + l)*8);
    bf16x8 b1 = *reinterpret_cast<const bf16x8*>(fG + (size_t)((nt*2+1)*64 + l)*8);
    acc[nt] = __builtin_amdgcn_mfma_f32_16x16x32_bf16(a0, b0, acc[nt], 0, 0, 0);
    acc[nt] = __builtin_amdgcn_mfma_f32_16x16x32_bf16(a1, b1, acc[nt], 0, 0, 0);
  }
  // attention dots: asrc/adst per (row, head)
  float asl[3][4], adl[3][4];
  #pragma unroll
  for (int h = 0; h < 3; ++h)
    #pragma unroll
    for (int u = 0; u < 4; ++u){
      asl[h][u] = a_src[h*64 + u*16 + b];
      adl[h][u] = a_dst[h*64 + u*16 + b];
    }
  #pragma unroll
  for (int r = 0; r < 4; ++r){
    int gr = row0 + w*16 + q*4 + r;
    #pragma unroll
    for (int h = 0; h < 3; ++h){
      float s = 0.f, d = 0.f;
      #pragma unroll
      for (int u = 0; u < 4; ++u){
        s = fmaf(acc[4*h+u][r], asl[h][u], s);
        d = fmaf(acc[4*h+u][r], adl[h][u], d);
      }
      s += __shfl_xor(s,1); s += __shfl_xor(s,2); s += __shfl_xor(s,4); s += __shfl_xor(s,8);
      d += __shfl_xor(d,1); d += __shfl_xor(d,2); d += __shfl_xor(d,4); d += __shfl_xor(d,8);
      if (b == h && gr < N_){ asrc[gr*3+h] = s; adst[gr*3+h] = d; }
    }
  }
  // xw -> LDS bf16 -> coalesced global
  #pragma unroll
  for (int nt = 0; nt < 12; ++nt){
    int col = nt*16 + b;
    #pragma unroll
    for (int r = 0; r < 4; ++r)
      sXW[(w*16 + q*4 + r)*196 + col] = f2bf(acc[nt][r]);
  }
  __syncthreads();
  #pragma unroll
  for (int i = 0; i < 12; ++i){
    int id = i*256 + t;
    int row = id / 48, cg = id % 48, gr = row0 + row;
    if (gr < N_){
      ushort4 pv = *reinterpret_cast<ushort4*>(&sXW[row*196 + cg*4]);
      *reinterpret_cast<ushort4*>(xw + (size_t)gr*192 + cg*4) = pv;
    }
  }
}

// per-node online-softmax attention aggregation: one wave per node.
// block 0 zeroes bn_stats for the following k_gru.
__global__ __launch_bounds__(256) void k_agg(
    const int* __restrict__ row_ptr, const int* __restrict__ src_s,
    const float* __restrict__ el_s,
    const float* __restrict__ asrc, const float* __restrict__ adst,
    const unsigned short* __restrict__ xw,
    const float* __restrict__ bg,
    float* __restrict__ mbuf, float* __restrict__ bn_stats)
{
  if (blockIdx.x == 0 && threadIdx.x < 128) bn_stats[threadIdx.x] = 0.f;
  int n = blockIdx.x*4 + (threadIdx.x >> 6);
  int c = threadIdx.x & 63;
  if (n >= N_) return;
  int p0 = row_ptr[n], p1 = row_ptr[n+1];
  float ad0 = adst[n*3+0], ad1 = adst[n*3+1], ad2 = adst[n*3+2];
  float m0 = -3.0e38f, m1 = -3.0e38f, m2 = -3.0e38f;
  float d0 = 0.f, d1 = 0.f, d2 = 0.f;
  float a0 = 0.f, a1 = 0.f, a2 = 0.f;
  for (int p = p0; p < p1; ++p){
    int s = src_s[p];
    float l0 = asrc[s*3+0] + ad0 + el_s[p*3+0];
    float l1 = asrc[s*3+1] + ad1 + el_s[p*3+1];
    float l2 = asrc[s*3+2] + ad2 + el_s[p*3+2];
    l0 = l0 > 0.f ? l0 : 0.2f*l0;
    l1 = l1 > 0.f ? l1 : 0.2f*l1;
    l2 = l2 > 0.f ? l2 : 0.2f*l2;
    const unsigned short* xp = xw + (size_t)s*192 + c;
    float v0 = bf2f(xp[0]), v1 = bf2f(xp[64]), v2 = bf2f(xp[128]);
    float nm, f, w;
    nm = fmaxf(m0,l0); f = __expf(m0-nm); w = __expf(l0-nm);
    d0 = d0*f + w; a0 = a0*f + w*v0; m0 = nm;
    nm = fmaxf(m1,l1); f = __expf(m1-nm); w = __expf(l1-nm);
    d1 = d1*f + w; a1 = a1*f + w*v1; m1 = nm;
    nm = fmaxf(m2,l2); f = __expf(m2-nm); w = __expf(l2-nm);
    d2 = d2*f + w; a2 = a2*f + w*v2; m2 = nm;
  }
  float mp = (a0/(d0+1e-16f) + a1/(d1+1e-16f) + a2/(d2+1e-16f)) * (1.0f/3.0f) + bg[c];
  mbuf[(size_t)n*64 + c] = mp > 0.f ? mp : (__expf(mp) - 1.0f);  // celu
}

// GRU step via MFMA: gi = m@Wih^T, gh = h@Whh^T, gates, h update; BN stats.
__global__ __launch_bounds__(256) void k_gru(
    const float* __restrict__ mbuf, const float* __restrict__ hsrc,
    float* __restrict__ hbuf,
    const unsigned short* __restrict__ fI, const unsigned short* __restrict__ fH,
    const float* __restrict__ bih, const float* __restrict__ bhh,
    float* __restrict__ bn_stats)
{
  __shared__ short sMf[8*64*8];
  __shared__ short sHf[8*64*8];
  __shared__ float sH[64][68];
  __shared__ float sStat[128];
  const int t = threadIdx.x;
  const int row0 = blockIdx.x * 64;
  if (t < 128) sStat[t] = 0.f;
  {
    const int lr = t >> 4, k4 = (t & 15) * 4;
    const int kt = k4 >> 5, lanew = lr + (((k4>>3)&3)<<4), j0 = k4 & 7;
    #pragma unroll
    for (int i = 0; i < 4; ++i){
      int r = lr + i*16, gr = row0 + r;
      float4 vm = make_float4(0.f,0.f,0.f,0.f), vh = vm;
      if (gr < N_){ vm = ldg4(mbuf + (size_t)gr*64 + k4); vh = ldg4(hsrc + (size_t)gr*64 + k4); }
      ushort4 pm; pm.x=f2bf(vm.x); pm.y=f2bf(vm.y); pm.z=f2bf(vm.z); pm.w=f2bf(vm.w);
      ushort4 ph; ph.x=f2bf(vh.x); ph.y=f2bf(vh.y); ph.z=f2bf(vh.z); ph.w=f2bf(vh.w);
      *reinterpret_cast<ushort4*>(&sMf[((i*2+kt)*64 + lanew)*8 + j0]) = pm;
      *reinterpret_cast<ushort4*>(&sHf[((i*2+kt)*64 + lanew)*8 + j0]) = ph;
      sH[r][k4+0]=vh.x; sH[r][k4+1]=vh.y; sH[r][k4+2]=vh.z; sH[r][k4+3]=vh.w;
    }
  }
  __syncthreads();
  const int w = t >> 6, l = t & 63, q = l >> 4, b = l & 15;
  f32x4 aI[12], aH[12];
  #pragma unroll
  for (int nt = 0; nt < 12; ++nt){ aI[nt] = (f32x4){0.f,0.f,0.f,0.f}; aH[nt] = (f32x4){0.f,0.f,0.f,0.f}; }
  bf16x8 am0 = *reinterpret_cast<bf16x8*>(&sMf[((w*2+0)*64 + l)*8]);
  bf16x8 am1 = *reinterpret_cast<bf16x8*>(&sMf[((w*2+1)*64 + l)*8]);
  bf16x8 ah0 = *reinterpret_cast<bf16x8*>(&sHf[((w*2+0)*64 + l)*8]);
  bf16x8 ah1 = *reinterpret_cast<bf16x8*>(&sHf[((w*2+1)*64 + l)*8]);
  #pragma unroll
  for (int nt = 0; nt < 12; ++nt){
    bf16x8 bI0 = *reinterpret_cast<const bf16x8*>(fI + (size_t)((nt*2+0)*64 + l)*8);
    bf16x8 bI1 = *reinterpret_cast<const bf16x8*>(fI + (size_t)((nt*2+1)*64 + l)*8);
    bf16x8 bH0 = *reinterpret_cast<const bf16x8*>(fH + (size_t)((nt*2+0)*64 + l)*8);
    bf16x8 bH1 = *reinterpret_cast<const bf16x8*>(fH + (size_t)((nt*2+1)*64 + l)*8);
    aI[nt] = __builtin_amdgcn_mfma_f32_16x16x32_bf16(am0, bI0, aI[nt], 0, 0, 0);
    aI[nt] = __builtin_amdgcn_mfma_f32_16x16x32_bf16(am1, bI1, aI[nt], 0, 0, 0);
    aH[nt] = __builtin_amdgcn_mfma_f32_16x16x32_bf16(ah0, bH0, aH[nt], 0, 0, 0);
    aH[nt] = __builtin_amdgcn_mfma_f32_16x16x32_bf16(ah1, bH1, aH[nt], 0, 0, 0);
  }
  float s1[4] = {0.f,0.f,0.f,0.f}, s2[4] = {0.f,0.f,0.f,0.f};
  #pragma unroll
  for (int tt = 0; tt < 4; ++tt){
    int c = tt*16 + b;
    float bir = bih[c], biz = bih[64+c], bin = bih[128+c];
    float bhr = bhh[c], bhz = bhh[64+c], bhn = bhh[128+c];
    #pragma unroll
    for (int r = 0; r < 4; ++r){
      int row = w*16 + q*4 + r, gr = row0 + row;
      float rg = sigmoidf_(aI[tt][r]   + bir + aH[tt][r]   + bhr);
      float zg = sigmoidf_(aI[tt+4][r] + biz + aH[tt+4][r] + bhz);
      float ng = tanhf(aI[tt+8][r] + bin + rg*(aH[tt+8][r] + bhn));
      float ho = sH[row][c];
      float hv = (1.f - zg)*ng + zg*ho;
      if (gr < N_){
        hbuf[(size_t)gr*64 + c] = hv;
        s1[tt] += hv; s2[tt] += hv*hv;
      }
    }
  }
  #pragma unroll
  for (int tt = 0; tt < 4; ++tt){
    float v = s1[tt];
    v += __shfl_xor(v, 16); v += __shfl_xor(v, 32);
    float u = s2[tt];
    u += __shfl_xor(u, 16); u += __shfl_xor(u, 32);
    if (q == 0){
      atomicAdd(&sStat[tt*16 + b], v);
      atomicAdd(&sStat[64 + tt*16 + b], u);
    }
  }
  __syncthreads();
  if (t < 128) atomicAdd(&bn_stats[t], sStat[t]);
}

// out = [feats(0..5) | bn(hbuf)] @ Wlin + blin via MFMA
__global__ __launch_bounds__(256) void k_final(
    const float* __restrict__ feats, const float* __restrict__ hbuf,
    const float* __restrict__ bn_stats,
    const float* __restrict__ gamma, const float* __restrict__ beta,
    const unsigned short* __restrict__ fL, const float* __restrict__ blin,
    float* __restrict__ out)
{
  __shared__ short sAf[8*64*8];
  __shared__ float sSc[64], sSh[64];
  const int t = threadIdx.x;
  const int row0 = blockIdx.x * 64;
  if (t < 64){
    float mu  = bn_stats[t] * (1.0f/30000.0f);
    float var = bn_stats[64+t] * (1.0f/30000.0f) - mu*mu;
    float rs = rsqrtf(var + 1e-5f);
    float sc = gamma[5*64 + t] * rs;
    sSc[t] = sc;
    sSh[t] = beta[5*64 + t] - mu*sc;
  }
  const int w = t >> 6, l = t & 63, q = l >> 4, b = l & 15;
  const int lr = t >> 4, k4 = (t & 15) * 4;
  const int kt = k4 >> 5, lanew = lr + (((k4>>3)&3)<<4), j0 = k4 & 7;
  f32x4 acc[4];
  #pragma unroll
  for (int nt = 0; nt < 4; ++nt) acc[nt] = (f32x4){0.f,0.f,0.f,0.f};
  for (int kc = 0; kc < 7; ++kc){
    __syncthreads();
    {
      #pragma unroll
      for (int i = 0; i < 4; ++i){
        int r = lr + i*16, gr = row0 + r;
        float4 v = make_float4(0.f,0.f,0.f,0.f);
        if (gr < N_){
          if (kc < 6) v = ldg4(feats + (size_t)gr*448 + kc*64 + k4);
          else {
            v = ldg4(hbuf + (size_t)gr*64 + k4);
            v.x = fmaf(v.x, sSc[k4+0], sSh[k4+0]);
            v.y = fmaf(v.y, sSc[k4+1], sSh[k4+1]);
            v.z = fmaf(v.z, sSc[k4+2], sSh[k4+2]);
            v.w = fmaf(v.w, sSc[k4+3], sSh[k4+3]);
          }
        }
        ushort4 pk; pk.x=f2bf(v.x); pk.y=f2bf(v.y); pk.z=f2bf(v.z); pk.w=f2bf(v.w);
        *reinterpret_cast<ushort4*>(&sAf[((i*2+kt)*64 + lanew)*8 + j0]) = pk;
      }
    }
    __syncthreads();
    bf16x8 a0 = *reinterpret_cast<bf16x8*>(&sAf[((w*2+0)*64 + l)*8]);
    bf16x8 a1 = *reinterpret_cast<bf16x8*>(&sAf[((w*2+1)*64 + l)*8]);
    #pragma unroll
    for (int nt = 0; nt < 4; ++nt){
      bf16x8 b0 = *reinterpret_cast<const bf16x8*>(fL + (size_t)((nt*14 + kc*2+0)*64 + l)*8);
      bf16x8 b1 = *reinterpret_cast<const bf16x8*>(fL + (size_t)((nt*14 + kc*2+1)*64 + l)*8);
      acc[nt] = __builtin_amdgcn_mfma_f32_16x16x32_bf16(a0, b0, acc[nt], 0, 0, 0);
      acc[nt] = __builtin_amdgcn_mfma_f32_16x16x32_bf16(a1, b1, acc[nt], 0, 0, 0);
    }
  }
  #pragma unroll
  for (int nt = 0; nt < 4; ++nt){
    int col = nt*16 + b;
    float bl = blin[col];
    #pragma unroll
    for (int r = 0; r < 4; ++r){
      int gr = row0 + w*16 + q*4 + r;
      if (gr < N_) out[(size_t)gr*64 + col] = acc[nt][r] + bl;
    }
  }
}

// ---------------- launch ----------------

extern "C" void kernel_launch(void* const* d_in, const int* in_sizes, int n_in,
                              void* d_out, int out_size, void* d_ws, size_t ws_size,
                              hipStream_t stream) {
  const float* x        = (const float*)d_in[0];
  const int*   ei       = (const int*)  d_in[1];
  const float* edge_attr= (const float*)d_in[2];
  const float* Wg       = (const float*)d_in[3];
  const float* bg       = (const float*)d_in[4];
  const float* a_src    = (const float*)d_in[5];
  const float* a_dst    = (const float*)d_in[6];
  const float* We       = (const float*)d_in[7];
  const float* a_edge   = (const float*)d_in[8];
  const float* Wih      = (const float*)d_in[9];
  const float* Whh      = (const float*)d_in[10];
  const float* bih      = (const float*)d_in[11];
  const float* bhh      = (const float*)d_in[12];
  const float* gamma    = (const float*)d_in[13];
  const float* beta     = (const float*)d_in[14];
  const float* Wlin     = (const float*)d_in[15];
  const float* blin     = (const float*)d_in[16];
  float* out = (float*)d_out;

  char* w = (char*)d_ws;
  auto alloc = [&](size_t bytes) -> void* {
    void* p = (void*)w;
    w += (bytes + 255) & ~(size_t)255;
    return p;
  };
  int*   row_ptr = (int*)  alloc((size_t)(N_+1)*4);
  int*   deg     = (int*)  alloc((size_t)N_*4);
  int*   cursor  = (int*)  alloc((size_t)N_*4);
  int*   partial = (int*)  alloc(128*4);
  int*   src_s   = (int*)  alloc((size_t)E_*4);
  float* el_s    = (float*)alloc((size_t)E_*3*4);
  float* Pw      = (float*)alloc(48*4);
  unsigned short* fG = (unsigned short*)alloc(12288*2);
  unsigned short* fI = (unsigned short*)alloc(12288*2);
  unsigned short* fH = (unsigned short*)alloc(12288*2);
  unsigned short* fL = (unsigned short*)alloc(28672*2);
  unsigned short* xw = (unsigned short*)alloc((size_t)N_*192*2);
  float* asrc    = (float*)alloc((size_t)N_*3*4);
  float* adst    = (float*)alloc((size_t)N_*3*4);
  float* mbuf    = (float*)alloc((size_t)N_*64*4);
  float* hbuf    = (float*)alloc((size_t)N_*64*4);
  float* feats   = (float*)alloc((size_t)N_*448*4);
  float* bn_stats= (float*)alloc(128*4);

  const int EB = (E_ + 255)/256;       // 1172
  const int GEMMB = (N_ + 63)/64;      // 469

  k_zero   <<<SCB, 256, 0, stream>>>(deg);
  k_wfrag  <<<257, 256, 0, stream>>>(Wg, Wih, Whh, Wlin, We, a_edge, fG, fI, fH, fL, Pw);
  k_hist   <<<EB, 256, 0, stream>>>(ei, deg);
  k_scanA  <<<SCB, 256, 0, stream>>>(deg, partial);
  k_scanB  <<<1, 128, 0, stream>>>(partial, row_ptr);
  k_scanC  <<<SCB, 256, 0, stream>>>(deg, partial, row_ptr, cursor);
  k_scatter<<<EB, 256, 0, stream>>>(ei, edge_attr, Pw, cursor, src_s, el_s);

  for (int step = 0; step < 6; ++step){
    const float* hsrc = (step == 0) ? x : hbuf;
    k_xw <<<GEMMB, 256, 0, stream>>>(hsrc, bn_stats, gamma, beta,
                                     step-1, step > 0 ? 1 : 0, step,
                                     fG, a_src, a_dst, xw, asrc, adst, feats);
    k_agg<<<(N_+3)/4, 256, 0, stream>>>(row_ptr, src_s, el_s, asrc, adst, xw, bg,
                                        mbuf, bn_stats);
    k_gru<<<GEMMB, 256, 0, stream>>>(mbuf, hsrc, hbuf, fI, fH, bih, bhh, bn_stats);
  }
  k_final<<<GEMMB, 256, 0, stream>>>(feats, hbuf, bn_stats, gamma, beta, fL, blin, out);
}

// Round 5
// 586.821 us; speedup vs baseline: 1.7047x; 1.1400x over previous
//
#include <hip/hip_runtime.h>
#include <math.h>

constexpr int N_ = 30000;
constexpr int E_ = 300000;
constexpr int SCB = (N_ + 255) / 256;   // 118 scan blocks

using f32x4  = __attribute__((ext_vector_type(4))) float;
using bf16x8 = __attribute__((ext_vector_type(8))) short;

__device__ __forceinline__ float4 ldg4(const float* p){ return *reinterpret_cast<const float4*>(p); }

__device__ __forceinline__ unsigned short f2bf(float f){
  union { float f; unsigned int u; } v; v.f = f;
  unsigned int r = v.u + 0x7FFFu + ((v.u >> 16) & 1u);
  return (unsigned short)(r >> 16);
}
__device__ __forceinline__ float bf2f(unsigned short b){
  union { unsigned int u; float f; } v; v.u = ((unsigned int)b) << 16;
  return v.f;
}
__device__ __forceinline__ float sigmoidf_(float x){ return 1.0f/(1.0f + __expf(-x)); }

// ---------------- setup kernels (once per launch) ----------------

__global__ void k_zero(int* __restrict__ deg){
  int i = blockIdx.x*256 + threadIdx.x;
  if (i < N_) deg[i] = 0;
}

// Build bf16 B-fragment weights for MFMA 16x16x32:
// frag element (nt,kt,l,j) = B[k = kt*32 + (l>>4)*8 + j][n = nt*16 + (l&15)]
// fG: B=Wg[64x192]; fI: B=Wih^T (Wih[192x64]); fH: B=Whh^T; fL: B=Wlin[448x64]
// block 256: P[j][h] = sum_c We[j,h*64+c]*a_edge[h,c]
__global__ void k_wfrag(const float* __restrict__ Wg, const float* __restrict__ Wih,
                        const float* __restrict__ Whh, const float* __restrict__ Wlin,
                        const float* __restrict__ We, const float* __restrict__ a_edge,
                        unsigned short* __restrict__ fG, unsigned short* __restrict__ fI,
                        unsigned short* __restrict__ fH, unsigned short* __restrict__ fL,
                        float* __restrict__ P){
  if (blockIdx.x == 256){
    int t = threadIdx.x; if (t >= 48) return;
    int j = t / 3, h = t % 3;
    float s = 0.f;
    for (int c = 0; c < 64; ++c) s += We[j*192 + h*64 + c] * a_edge[h*64 + c];
    P[j*3 + h] = s;
    return;
  }
  int id = blockIdx.x*256 + threadIdx.x;   // 0..65535
  int lid, KT;
  unsigned short* dst; int mode;
  if (id < 12288)      { lid = id;         KT = 2;  dst = fG; mode = 0; }
  else if (id < 24576) { lid = id - 12288; KT = 2;  dst = fI; mode = 1; }
  else if (id < 36864) { lid = id - 24576; KT = 2;  dst = fH; mode = 2; }
  else                 { lid = id - 36864; KT = 14; dst = fL; mode = 3; }
  int j = lid & 7, l = (lid >> 3) & 63, rest = lid >> 9;
  int kt = rest % KT, nt = rest / KT;
  int k = kt*32 + (l>>4)*8 + j;
  int n = nt*16 + (l&15);
  float v;
  if (mode == 0)      v = Wg[k*192 + n];
  else if (mode == 1) v = Wih[n*64 + k];
  else if (mode == 2) v = Whh[n*64 + k];
  else                v = Wlin[k*64 + n];
  dst[lid] = f2bf(v);
}

__global__ void k_hist(const int* __restrict__ ei, int* __restrict__ deg){
  int e = blockIdx.x*256 + threadIdx.x;
  if (e < E_) atomicAdd(&deg[ei[E_ + e]], 1);
}

__global__ void k_scanA(const int* __restrict__ deg, int* __restrict__ partial){
  int i = blockIdx.x*256 + threadIdx.x;
  int v = (i < N_) ? deg[i] : 0;
  #pragma unroll
  for (int off = 1; off < 64; off <<= 1) v += __shfl_xor(v, off);
  __shared__ int ws[4];
  if ((threadIdx.x & 63) == 0) ws[threadIdx.x >> 6] = v;
  __syncthreads();
  if (threadIdx.x == 0) partial[blockIdx.x] = ws[0] + ws[1] + ws[2] + ws[3];
}

__global__ void k_scanB(int* __restrict__ partial, int* __restrict__ row_ptr){
  __shared__ int s[128];
  int t = threadIdx.x;
  int v = (t < SCB) ? partial[t] : 0;
  s[t] = v; __syncthreads();
  for (int off = 1; off < 128; off <<= 1){
    int u = (t >= off) ? s[t-off] : 0;
    __syncthreads();
    s[t] += u;
    __syncthreads();
  }
  if (t < SCB) partial[t] = s[t] - v;   // exclusive
  if (t == 0) row_ptr[N_] = E_;
}

__global__ void k_scanC(const int* __restrict__ deg, const int* __restrict__ partial,
                        int* __restrict__ row_ptr, int* __restrict__ cursor){
  __shared__ int s[256];
  int t = threadIdx.x, i = blockIdx.x*256 + t;
  int v = (i < N_) ? deg[i] : 0;
  s[t] = v; __syncthreads();
  for (int off = 1; off < 256; off <<= 1){
    int u = (t >= off) ? s[t-off] : 0;
    __syncthreads();
    s[t] += u;
    __syncthreads();
  }
  int ex = s[t] - v + partial[blockIdx.x];
  if (i < N_){ row_ptr[i] = ex; cursor[i] = ex; }
}

// fused: edge logit term (edge_attr @ P) + CSR scatter (also records dst)
__global__ void k_scatter(const int* __restrict__ ei, const float* __restrict__ edge_attr,
                          const float* __restrict__ P,
                          int* __restrict__ cursor, int* __restrict__ src_s,
                          int* __restrict__ dst_s, float* __restrict__ el_s){
  __shared__ float sP[48];
  int t = threadIdx.x;
  if (t < 48) sP[t] = P[t];
  __syncthreads();
  int e = blockIdx.x*256 + t;
  if (e >= E_) return;
  const float* ea = edge_attr + (size_t)e*16;
  float v[16];
  #pragma unroll
  for (int q = 0; q < 4; ++q){
    float4 f = ldg4(ea + q*4);
    v[q*4+0]=f.x; v[q*4+1]=f.y; v[q*4+2]=f.z; v[q*4+3]=f.w;
  }
  float l0=0.f,l1=0.f,l2=0.f;
  #pragma unroll
  for (int j = 0; j < 16; ++j){
    l0 += v[j]*sP[j*3+0]; l1 += v[j]*sP[j*3+1]; l2 += v[j]*sP[j*3+2];
  }
  int d = ei[E_ + e];
  int p = atomicAdd(&cursor[d], 1);
  src_s[p] = ei[e];
  dst_s[p] = d;
  el_s[p*3+0] = l0; el_s[p*3+1] = l1; el_s[p*3+2] = l2;
}

// ---------------- per-step kernels ----------------

// fused BN(hsrc)->feats + xw = bn(x)@Wg via MFMA + alpha dots
__global__ __launch_bounds__(256) void k_xw(
    const float* __restrict__ hsrc,
    const float* __restrict__ bn_stats,
    const float* __restrict__ gamma, const float* __restrict__ beta,
    int gidx, int bn, int slot,
    const unsigned short* __restrict__ fG,
    const float* __restrict__ a_src, const float* __restrict__ a_dst,
    unsigned short* __restrict__ xw,
    float* __restrict__ asrc, float* __restrict__ adst,
    float* __restrict__ feats)
{
  __shared__ short sAf[8*64*8];        // A-frag bf16, 8 KB
  __shared__ unsigned short sXW[64*196];
  __shared__ float sSc[64], sSh[64];
  const int t = threadIdx.x;
  const int row0 = blockIdx.x * 64;
  if (t < 64){
    float sc = 1.f, sh = 0.f;
    if (bn){
      float mu  = bn_stats[t] * (1.0f/30000.0f);
      float var = bn_stats[64+t] * (1.0f/30000.0f) - mu*mu;
      float rs = rsqrtf(var + 1e-5f);
      sc = gamma[gidx*64 + t] * rs;
      sh = beta[gidx*64 + t] - mu*sc;
    }
    sSc[t] = sc; sSh[t] = sh;
  }
  __syncthreads();
  {
    const int lr = t >> 4, k4 = (t & 15) * 4;
    const float sc0=sSc[k4],sc1=sSc[k4+1],sc2=sSc[k4+2],sc3=sSc[k4+3];
    const float sh0=sSh[k4],sh1=sSh[k4+1],sh2=sSh[k4+2],sh3=sSh[k4+3];
    const int kt = k4 >> 5, lanew = lr + (((k4>>3)&3)<<4), j0 = k4 & 7;
    #pragma unroll
    for (int i = 0; i < 4; ++i){
      int r = lr + i*16, gr = row0 + r;
      float4 v = make_float4(0.f,0.f,0.f,0.f);
      if (gr < N_){
        v = ldg4(hsrc + (size_t)gr*64 + k4);
        v.x = fmaf(v.x, sc0, sh0); v.y = fmaf(v.y, sc1, sh1);
        v.z = fmaf(v.z, sc2, sh2); v.w = fmaf(v.w, sc3, sh3);
        *reinterpret_cast<float4*>(feats + (size_t)gr*448 + slot*64 + k4) = v;
      }
      ushort4 pk; pk.x=f2bf(v.x); pk.y=f2bf(v.y); pk.z=f2bf(v.z); pk.w=f2bf(v.w);
      *reinterpret_cast<ushort4*>(&sAf[((i*2+kt)*64 + lanew)*8 + j0]) = pk;
    }
  }
  __syncthreads();
  const int w = t >> 6, l = t & 63, q = l >> 4, b = l & 15;
  f32x4 acc[12];
  #pragma unroll
  for (int nt = 0; nt < 12; ++nt) acc[nt] = (f32x4){0.f,0.f,0.f,0.f};
  bf16x8 a0 = *reinterpret_cast<bf16x8*>(&sAf[((w*2+0)*64 + l)*8]);
  bf16x8 a1 = *reinterpret_cast<bf16x8*>(&sAf[((w*2+1)*64 + l)*8]);
  #pragma unroll
  for (int nt = 0; nt < 12; ++nt){
    bf16x8 b0 = *reinterpret_cast<const bf16x8*>(fG + (size_t)((nt*2+0)*64 + l)*8);
    bf16x8 b1 = *reinterpret_cast<const bf16x8*>(fG + (size_t)((nt*2+1)*64 + l)*8);
    acc[nt] = __builtin_amdgcn_mfma_f32_16x16x32_bf16(a0, b0, acc[nt], 0, 0, 0);
    acc[nt] = __builtin_amdgcn_mfma_f32_16x16x32_bf16(a1, b1, acc[nt], 0, 0, 0);
  }
  // attention dots: asrc/adst per (row, head)
  float asl[3][4], adl[3][4];
  #pragma unroll
  for (int h = 0; h < 3; ++h)
    #pragma unroll
    for (int u = 0; u < 4; ++u){
      asl[h][u] = a_src[h*64 + u*16 + b];
      adl[h][u] = a_dst[h*64 + u*16 + b];
    }
  #pragma unroll
  for (int r = 0; r < 4; ++r){
    int gr = row0 + w*16 + q*4 + r;
    #pragma unroll
    for (int h = 0; h < 3; ++h){
      float s = 0.f, d = 0.f;
      #pragma unroll
      for (int u = 0; u < 4; ++u){
        s = fmaf(acc[4*h+u][r], asl[h][u], s);
        d = fmaf(acc[4*h+u][r], adl[h][u], d);
      }
      s += __shfl_xor(s,1); s += __shfl_xor(s,2); s += __shfl_xor(s,4); s += __shfl_xor(s,8);
      d += __shfl_xor(d,1); d += __shfl_xor(d,2); d += __shfl_xor(d,4); d += __shfl_xor(d,8);
      if (b == h && gr < N_){ asrc[gr*3+h] = s; adst[gr*3+h] = d; }
    }
  }
  // xw -> LDS bf16 -> coalesced global
  #pragma unroll
  for (int nt = 0; nt < 12; ++nt){
    int col = nt*16 + b;
    #pragma unroll
    for (int r = 0; r < 4; ++r)
      sXW[(w*16 + q*4 + r)*196 + col] = f2bf(acc[nt][r]);
  }
  __syncthreads();
  #pragma unroll
  for (int i = 0; i < 12; ++i){
    int id = i*256 + t;
    int row = id / 48, cg = id % 48, gr = row0 + row;
    if (gr < N_){
      ushort4 pv = *reinterpret_cast<ushort4*>(&sXW[row*196 + cg*4]);
      *reinterpret_cast<ushort4*>(xw + (size_t)gr*192 + cg*4) = pv;
    }
  }
}

// edge-parallel attention weights: att = exp(leaky_relu(asrc+adst+el))
// (no max-subtraction: algebraically identical softmax; logits are O(+-8))
__global__ void k_att(const int* __restrict__ src_s, const int* __restrict__ dst_s,
                      const float* __restrict__ el_s,
                      const float* __restrict__ asrc, const float* __restrict__ adst,
                      float* __restrict__ att_s){
  int p = blockIdx.x*256 + threadIdx.x;
  if (p >= E_) return;
  int s = src_s[p], d = dst_s[p];
  #pragma unroll
  for (int h = 0; h < 3; ++h){
    float l = asrc[s*3+h] + adst[d*3+h] + el_s[p*3+h];
    l = l > 0.f ? l : 0.2f*l;
    att_s[p*3+h] = __expf(l);
  }
}

// per-node weighted aggregation: one wave per node, weights precomputed.
// block 0 zeroes bn_stats for the following k_gru.
__global__ __launch_bounds__(256) void k_agg(
    const int* __restrict__ row_ptr, const int* __restrict__ src_s,
    const float* __restrict__ att_s,
    const unsigned short* __restrict__ xw,
    const float* __restrict__ bg,
    float* __restrict__ mbuf, float* __restrict__ bn_stats)
{
  if (blockIdx.x == 0 && threadIdx.x < 128) bn_stats[threadIdx.x] = 0.f;
  int n = blockIdx.x*4 + (threadIdx.x >> 6);
  int c = threadIdx.x & 63;
  if (n >= N_) return;
  int p0 = row_ptr[n], p1 = row_ptr[n+1];
  float d0 = 0.f, d1 = 0.f, d2 = 0.f;
  float a0 = 0.f, a1 = 0.f, a2 = 0.f;
  int p = p0;
  for (; p + 2 <= p1; p += 2){
    int sA = src_s[p], sB = src_s[p+1];
    float wA0 = att_s[p*3+0], wA1 = att_s[p*3+1], wA2 = att_s[p*3+2];
    float wB0 = att_s[p*3+3], wB1 = att_s[p*3+4], wB2 = att_s[p*3+5];
    const unsigned short* xpA = xw + (size_t)sA*192 + c;
    const unsigned short* xpB = xw + (size_t)sB*192 + c;
    float vA0 = bf2f(xpA[0]), vA1 = bf2f(xpA[64]), vA2 = bf2f(xpA[128]);
    float vB0 = bf2f(xpB[0]), vB1 = bf2f(xpB[64]), vB2 = bf2f(xpB[128]);
    d0 += wA0 + wB0; d1 += wA1 + wB1; d2 += wA2 + wB2;
    a0 = fmaf(wA0, vA0, a0); a1 = fmaf(wA1, vA1, a1); a2 = fmaf(wA2, vA2, a2);
    a0 = fmaf(wB0, vB0, a0); a1 = fmaf(wB1, vB1, a1); a2 = fmaf(wB2, vB2, a2);
  }
  if (p < p1){
    int s = src_s[p];
    float w0 = att_s[p*3+0], w1 = att_s[p*3+1], w2 = att_s[p*3+2];
    const unsigned short* xp = xw + (size_t)s*192 + c;
    d0 += w0; d1 += w1; d2 += w2;
    a0 = fmaf(w0, bf2f(xp[0]), a0);
    a1 = fmaf(w1, bf2f(xp[64]), a1);
    a2 = fmaf(w2, bf2f(xp[128]), a2);
  }
  float mp = (a0/(d0+1e-16f) + a1/(d1+1e-16f) + a2/(d2+1e-16f)) * (1.0f/3.0f) + bg[c];
  mbuf[(size_t)n*64 + c] = mp > 0.f ? mp : (__expf(mp) - 1.0f);  // celu
}

// GRU step via MFMA: gi = m@Wih^T, gh = h@Whh^T, gates, h update; BN stats.
__global__ __launch_bounds__(256) void k_gru(
    const float* __restrict__ mbuf, const float* __restrict__ hsrc,
    float* __restrict__ hbuf,
    const unsigned short* __restrict__ fI, const unsigned short* __restrict__ fH,
    const float* __restrict__ bih, const float* __restrict__ bhh,
    float* __restrict__ bn_stats)
{
  __shared__ short sMf[8*64*8];
  __shared__ short sHf[8*64*8];
  __shared__ float sH[64][68];
  __shared__ float sStat[128];
  const int t = threadIdx.x;
  const int row0 = blockIdx.x * 64;
  if (t < 128) sStat[t] = 0.f;
  {
    const int lr = t >> 4, k4 = (t & 15) * 4;
    const int kt = k4 >> 5, lanew = lr + (((k4>>3)&3)<<4), j0 = k4 & 7;
    #pragma unroll
    for (int i = 0; i < 4; ++i){
      int r = lr + i*16, gr = row0 + r;
      float4 vm = make_float4(0.f,0.f,0.f,0.f), vh = vm;
      if (gr < N_){ vm = ldg4(mbuf + (size_t)gr*64 + k4); vh = ldg4(hsrc + (size_t)gr*64 + k4); }
      ushort4 pm; pm.x=f2bf(vm.x); pm.y=f2bf(vm.y); pm.z=f2bf(vm.z); pm.w=f2bf(vm.w);
      ushort4 ph; ph.x=f2bf(vh.x); ph.y=f2bf(vh.y); ph.z=f2bf(vh.z); ph.w=f2bf(vh.w);
      *reinterpret_cast<ushort4*>(&sMf[((i*2+kt)*64 + lanew)*8 + j0]) = pm;
      *reinterpret_cast<ushort4*>(&sHf[((i*2+kt)*64 + lanew)*8 + j0]) = ph;
      sH[r][k4+0]=vh.x; sH[r][k4+1]=vh.y; sH[r][k4+2]=vh.z; sH[r][k4+3]=vh.w;
    }
  }
  __syncthreads();
  const int w = t >> 6, l = t & 63, q = l >> 4, b = l & 15;
  f32x4 aI[12], aH[12];
  #pragma unroll
  for (int nt = 0; nt < 12; ++nt){ aI[nt] = (f32x4){0.f,0.f,0.f,0.f}; aH[nt] = (f32x4){0.f,0.f,0.f,0.f}; }
  bf16x8 am0 = *reinterpret_cast<bf16x8*>(&sMf[((w*2+0)*64 + l)*8]);
  bf16x8 am1 = *reinterpret_cast<bf16x8*>(&sMf[((w*2+1)*64 + l)*8]);
  bf16x8 ah0 = *reinterpret_cast<bf16x8*>(&sHf[((w*2+0)*64 + l)*8]);
  bf16x8 ah1 = *reinterpret_cast<bf16x8*>(&sHf[((w*2+1)*64 + l)*8]);
  #pragma unroll
  for (int nt = 0; nt < 12; ++nt){
    bf16x8 bI0 = *reinterpret_cast<const bf16x8*>(fI + (size_t)((nt*2+0)*64 + l)*8);
    bf16x8 bI1 = *reinterpret_cast<const bf16x8*>(fI + (size_t)((nt*2+1)*64 + l)*8);
    bf16x8 bH0 = *reinterpret_cast<const bf16x8*>(fH + (size_t)((nt*2+0)*64 + l)*8);
    bf16x8 bH1 = *reinterpret_cast<const bf16x8*>(fH + (size_t)((nt*2+1)*64 + l)*8);
    aI[nt] = __builtin_amdgcn_mfma_f32_16x16x32_bf16(am0, bI0, aI[nt], 0, 0, 0);
    aI[nt] = __builtin_amdgcn_mfma_f32_16x16x32_bf16(am1, bI1, aI[nt], 0, 0, 0);
    aH[nt] = __builtin_amdgcn_mfma_f32_16x16x32_bf16(ah0, bH0, aH[nt], 0, 0, 0);
    aH[nt] = __builtin_amdgcn_mfma_f32_16x16x32_bf16(ah1, bH1, aH[nt], 0, 0, 0);
  }
  float s1[4] = {0.f,0.f,0.f,0.f}, s2[4] = {0.f,0.f,0.f,0.f};
  #pragma unroll
  for (int tt = 0; tt < 4; ++tt){
    int c = tt*16 + b;
    float bir = bih[c], biz = bih[64+c], bin = bih[128+c];
    float bhr = bhh[c], bhz = bhh[64+c], bhn = bhh[128+c];
    #pragma unroll
    for (int r = 0; r < 4; ++r){
      int row = w*16 + q*4 + r, gr = row0 + row;
      float rg = sigmoidf_(aI[tt][r]   + bir + aH[tt][r]   + bhr);
      float zg = sigmoidf_(aI[tt+4][r] + biz + aH[tt+4][r] + bhz);
      float ng = tanhf(aI[tt+8][r] + bin + rg*(aH[tt+8][r] + bhn));
      float ho = sH[row][c];
      float hv = (1.f - zg)*ng + zg*ho;
      if (gr < N_){
        hbuf[(size_t)gr*64 + c] = hv;
        s1[tt] += hv; s2[tt] += hv*hv;
      }
    }
  }
  #pragma unroll
  for (int tt = 0; tt < 4; ++tt){
    float v = s1[tt];
    v += __shfl_xor(v, 16); v += __shfl_xor(v, 32);
    float u = s2[tt];
    u += __shfl_xor(u, 16); u += __shfl_xor(u, 32);
    if (q == 0){
      atomicAdd(&sStat[tt*16 + b], v);
      atomicAdd(&sStat[64 + tt*16 + b], u);
    }
  }
  __syncthreads();
  if (t < 128) atomicAdd(&bn_stats[t], sStat[t]);
}

// out = [feats(0..5) | bn(hbuf)] @ Wlin + blin via MFMA
__global__ __launch_bounds__(256) void k_final(
    const float* __restrict__ feats, const float* __restrict__ hbuf,
    const float* __restrict__ bn_stats,
    const float* __restrict__ gamma, const float* __restrict__ beta,
    const unsigned short* __restrict__ fL, const float* __restrict__ blin,
    float* __restrict__ out)
{
  __shared__ short sAf[8*64*8];
  __shared__ float sSc[64], sSh[64];
  const int t = threadIdx.x;
  const int row0 = blockIdx.x * 64;
  if (t < 64){
    float mu  = bn_stats[t] * (1.0f/30000.0f);
    float var = bn_stats[64+t] * (1.0f/30000.0f) - mu*mu;
    float rs = rsqrtf(var + 1e-5f);
    float sc = gamma[5*64 + t] * rs;
    sSc[t] = sc;
    sSh[t] = beta[5*64 + t] - mu*sc;
  }
  const int w = t >> 6, l = t & 63, q = l >> 4, b = l & 15;
  const int lr = t >> 4, k4 = (t & 15) * 4;
  const int kt = k4 >> 5, lanew = lr + (((k4>>3)&3)<<4), j0 = k4 & 7;
  f32x4 acc[4];
  #pragma unroll
  for (int nt = 0; nt < 4; ++nt) acc[nt] = (f32x4){0.f,0.f,0.f,0.f};
  for (int kc = 0; kc < 7; ++kc){
    __syncthreads();
    {
      #pragma unroll
      for (int i = 0; i < 4; ++i){
        int r = lr + i*16, gr = row0 + r;
        float4 v = make_float4(0.f,0.f,0.f,0.f);
        if (gr < N_){
          if (kc < 6) v = ldg4(feats + (size_t)gr*448 + kc*64 + k4);
          else {
            v = ldg4(hbuf + (size_t)gr*64 + k4);
            v.x = fmaf(v.x, sSc[k4+0], sSh[k4+0]);
            v.y = fmaf(v.y, sSc[k4+1], sSh[k4+1]);
            v.z = fmaf(v.z, sSc[k4+2], sSh[k4+2]);
            v.w = fmaf(v.w, sSc[k4+3], sSh[k4+3]);
          }
        }
        ushort4 pk; pk.x=f2bf(v.x); pk.y=f2bf(v.y); pk.z=f2bf(v.z); pk.w=f2bf(v.w);
        *reinterpret_cast<ushort4*>(&sAf[((i*2+kt)*64 + lanew)*8 + j0]) = pk;
      }
    }
    __syncthreads();
    bf16x8 a0 = *reinterpret_cast<bf16x8*>(&sAf[((w*2+0)*64 + l)*8]);
    bf16x8 a1 = *reinterpret_cast<bf16x8*>(&sAf[((w*2+1)*64 + l)*8]);
    #pragma unroll
    for (int nt = 0; nt < 4; ++nt){
      bf16x8 b0 = *reinterpret_cast<const bf16x8*>(fL + (size_t)((nt*14 + kc*2+0)*64 + l)*8);
      bf16x8 b1 = *reinterpret_cast<const bf16x8*>(fL + (size_t)((nt*14 + kc*2+1)*64 + l)*8);
      acc[nt] = __builtin_amdgcn_mfma_f32_16x16x32_bf16(a0, b0, acc[nt], 0, 0, 0);
      acc[nt] = __builtin_amdgcn_mfma_f32_16x16x32_bf16(a1, b1, acc[nt], 0, 0, 0);
    }
  }
  #pragma unroll
  for (int nt = 0; nt < 4; ++nt){
    int col = nt*16 + b;
    float bl = blin[col];
    #pragma unroll
    for (int r = 0; r < 4; ++r){
      int gr = row0 + w*16 + q*4 + r;
      if (gr < N_) out[(size_t)gr*64 + col] = acc[nt][r] + bl;
    }
  }
}

// ---------------- launch ----------------

extern "C" void kernel_launch(void* const* d_in, const int* in_sizes, int n_in,
                              void* d_out, int out_size, void* d_ws, size_t ws_size,
                              hipStream_t stream) {
  const float* x        = (const float*)d_in[0];
  const int*   ei       = (const int*)  d_in[1];
  const float* edge_attr= (const float*)d_in[2];
  const float* Wg       = (const float*)d_in[3];
  const float* bg       = (const float*)d_in[4];
  const float* a_src    = (const float*)d_in[5];
  const float* a_dst    = (const float*)d_in[6];
  const float* We       = (const float*)d_in[7];
  const float* a_edge   = (const float*)d_in[8];
  const float* Wih      = (const float*)d_in[9];
  const float* Whh      = (const float*)d_in[10];
  const float* bih      = (const float*)d_in[11];
  const float* bhh      = (const float*)d_in[12];
  const float* gamma    = (const float*)d_in[13];
  const float* beta     = (const float*)d_in[14];
  const float* Wlin     = (const float*)d_in[15];
  const float* blin     = (const float*)d_in[16];
  float* out = (float*)d_out;

  char* w = (char*)d_ws;
  auto alloc = [&](size_t bytes) -> void* {
    void* p = (void*)w;
    w += (bytes + 255) & ~(size_t)255;
    return p;
  };
  int*   row_ptr = (int*)  alloc((size_t)(N_+1)*4);
  int*   deg     = (int*)  alloc((size_t)N_*4);
  int*   cursor  = (int*)  alloc((size_t)N_*4);
  int*   partial = (int*)  alloc(128*4);
  int*   src_s   = (int*)  alloc((size_t)E_*4);
  int*   dst_s   = (int*)  alloc((size_t)E_*4);
  float* el_s    = (float*)alloc((size_t)E_*3*4);
  float* att_s   = (float*)alloc((size_t)E_*3*4);
  float* Pw      = (float*)alloc(48*4);
  unsigned short* fG = (unsigned short*)alloc(12288*2);
  unsigned short* fI = (unsigned short*)alloc(12288*2);
  unsigned short* fH = (unsigned short*)alloc(12288*2);
  unsigned short* fL = (unsigned short*)alloc(28672*2);
  unsigned short* xw = (unsigned short*)alloc((size_t)N_*192*2);
  float* asrc    = (float*)alloc((size_t)N_*3*4);
  float* adst    = (float*)alloc((size_t)N_*3*4);
  float* mbuf    = (float*)alloc((size_t)N_*64*4);
  float* hbuf    = (float*)alloc((size_t)N_*64*4);
  float* feats   = (float*)alloc((size_t)N_*448*4);
  float* bn_stats= (float*)alloc(128*4);

  const int EB = (E_ + 255)/256;       // 1172
  const int GEMMB = (N_ + 63)/64;      // 469

  k_zero   <<<SCB, 256, 0, stream>>>(deg);
  k_wfrag  <<<257, 256, 0, stream>>>(Wg, Wih, Whh, Wlin, We, a_edge, fG, fI, fH, fL, Pw);
  k_hist   <<<EB, 256, 0, stream>>>(ei, deg);
  k_scanA  <<<SCB, 256, 0, stream>>>(deg, partial);
  k_scanB  <<<1, 128, 0, stream>>>(partial, row_ptr);
  k_scanC  <<<SCB, 256, 0, stream>>>(deg, partial, row_ptr, cursor);
  k_scatter<<<EB, 256, 0, stream>>>(ei, edge_attr, Pw, cursor, src_s, dst_s, el_s);

  for (int step = 0; step < 6; ++step){
    const float* hsrc = (step == 0) ? x : hbuf;
    k_xw <<<GEMMB, 256, 0, stream>>>(hsrc, bn_stats, gamma, beta,
                                     step-1, step > 0 ? 1 : 0, step,
                                     fG, a_src, a_dst, xw, asrc, adst, feats);
    k_att<<<EB, 256, 0, stream>>>(src_s, dst_s, el_s, asrc, adst, att_s);
    k_agg<<<(N_+3)/4, 256, 0, stream>>>(row_ptr, src_s, att_s, xw, bg, mbuf, bn_stats);
    k_gru<<<GEMMB, 256, 0, stream>>>(mbuf, hsrc, hbuf, fI, fH, bih, bhh, bn_stats);
  }
  k_final<<<GEMMB, 256, 0, stream>>>(feats, hbuf, bn_stats, gamma, beta, fL, blin, out);
}

// Round 6
// 558.995 us; speedup vs baseline: 1.7895x; 1.0498x over previous
//
#include <hip/hip_runtime.h>
#include <math.h>

constexpr int N_ = 30000;
constexpr int E_ = 300000;
constexpr int SCB = (N_ + 255) / 256;   // 118 scan blocks
constexpr int GB_ = (N_ + 63) / 64;     // 469 GEMM blocks

using f32x4  = __attribute__((ext_vector_type(4))) float;
using bf16x8 = __attribute__((ext_vector_type(8))) short;

__device__ __forceinline__ float4 ldg4(const float* p){ return *reinterpret_cast<const float4*>(p); }

__device__ __forceinline__ unsigned short f2bf(float f){
  union { float f; unsigned int u; } v; v.f = f;
  unsigned int r = v.u + 0x7FFFu + ((v.u >> 16) & 1u);
  return (unsigned short)(r >> 16);
}
__device__ __forceinline__ float bf2f(unsigned short b){
  union { unsigned int u; float f; } v; v.u = ((unsigned int)b) << 16;
  return v.f;
}
__device__ __forceinline__ float sigmoidf_(float x){ return 1.0f/(1.0f + __expf(-x)); }

// ---------------- setup kernels (once per launch) ----------------

// blocks 0..255: bf16 B-fragment weights for MFMA 16x16x32
//   frag element (nt,kt,l,j) = B[k = kt*32 + (l>>4)*8 + j][n = nt*16 + (l&15)]
//   fG: B=Wg[64x192]; fI: B=Wih^T; fH: B=Whh^T; fL: B=Wlin[448x64]
// block 256: P[j][h] = sum_c We[j,h*64+c]*a_edge[h,c]
// blocks 257..374: zero deg
__global__ void k_wfrag(const float* __restrict__ Wg, const float* __restrict__ Wih,
                        const float* __restrict__ Whh, const float* __restrict__ Wlin,
                        const float* __restrict__ We, const float* __restrict__ a_edge,
                        unsigned short* __restrict__ fG, unsigned short* __restrict__ fI,
                        unsigned short* __restrict__ fH, unsigned short* __restrict__ fL,
                        float* __restrict__ P, int* __restrict__ deg){
  if (blockIdx.x >= 257){
    int i = (blockIdx.x - 257)*256 + threadIdx.x;
    if (i < N_) deg[i] = 0;
    return;
  }
  if (blockIdx.x == 256){
    int t = threadIdx.x; if (t >= 48) return;
    int j = t / 3, h = t % 3;
    float s = 0.f;
    for (int c = 0; c < 64; ++c) s += We[j*192 + h*64 + c] * a_edge[h*64 + c];
    P[j*3 + h] = s;
    return;
  }
  int id = blockIdx.x*256 + threadIdx.x;   // 0..65535
  int lid, KT;
  unsigned short* dst; int mode;
  if (id < 12288)      { lid = id;         KT = 2;  dst = fG; mode = 0; }
  else if (id < 24576) { lid = id - 12288; KT = 2;  dst = fI; mode = 1; }
  else if (id < 36864) { lid = id - 24576; KT = 2;  dst = fH; mode = 2; }
  else                 { lid = id - 36864; KT = 14; dst = fL; mode = 3; }
  int j = lid & 7, l = (lid >> 3) & 63, rest = lid >> 9;
  int kt = rest % KT, nt = rest / KT;
  int k = kt*32 + (l>>4)*8 + j;
  int n = nt*16 + (l&15);
  float v;
  if (mode == 0)      v = Wg[k*192 + n];
  else if (mode == 1) v = Wih[n*64 + k];
  else if (mode == 2) v = Whh[n*64 + k];
  else                v = Wlin[k*64 + n];
  dst[lid] = f2bf(v);
}

__global__ void k_hist(const int* __restrict__ ei, int* __restrict__ deg){
  int e = blockIdx.x*256 + threadIdx.x;
  if (e < E_) atomicAdd(&deg[ei[E_ + e]], 1);
}

__global__ void k_scanA(const int* __restrict__ deg, int* __restrict__ partial){
  int i = blockIdx.x*256 + threadIdx.x;
  int v = (i < N_) ? deg[i] : 0;
  #pragma unroll
  for (int off = 1; off < 64; off <<= 1) v += __shfl_xor(v, off);
  __shared__ int ws[4];
  if ((threadIdx.x & 63) == 0) ws[threadIdx.x >> 6] = v;
  __syncthreads();
  if (threadIdx.x == 0) partial[blockIdx.x] = ws[0] + ws[1] + ws[2] + ws[3];
}

__global__ void k_scanB(int* __restrict__ partial, int* __restrict__ row_ptr){
  __shared__ int s[128];
  int t = threadIdx.x;
  int v = (t < SCB) ? partial[t] : 0;
  s[t] = v; __syncthreads();
  for (int off = 1; off < 128; off <<= 1){
    int u = (t >= off) ? s[t-off] : 0;
    __syncthreads();
    s[t] += u;
    __syncthreads();
  }
  if (t < SCB) partial[t] = s[t] - v;   // exclusive
  if (t == 0) row_ptr[N_] = E_;
}

__global__ void k_scanC(const int* __restrict__ deg, const int* __restrict__ partial,
                        int* __restrict__ row_ptr, int* __restrict__ cursor){
  __shared__ int s[256];
  int t = threadIdx.x, i = blockIdx.x*256 + t;
  int v = (i < N_) ? deg[i] : 0;
  s[t] = v; __syncthreads();
  for (int off = 1; off < 256; off <<= 1){
    int u = (t >= off) ? s[t-off] : 0;
    __syncthreads();
    s[t] += u;
    __syncthreads();
  }
  int ex = s[t] - v + partial[blockIdx.x];
  if (i < N_){ row_ptr[i] = ex; cursor[i] = ex; }
}

// fused: edge logit term (edge_attr @ P) + CSR scatter (also records dst)
__global__ void k_scatter(const int* __restrict__ ei, const float* __restrict__ edge_attr,
                          const float* __restrict__ P,
                          int* __restrict__ cursor, int* __restrict__ src_s,
                          int* __restrict__ dst_s, float* __restrict__ el_s){
  __shared__ float sP[48];
  int t = threadIdx.x;
  if (t < 48) sP[t] = P[t];
  __syncthreads();
  int e = blockIdx.x*256 + t;
  if (e >= E_) return;
  const float* ea = edge_attr + (size_t)e*16;
  float v[16];
  #pragma unroll
  for (int q = 0; q < 4; ++q){
    float4 f = ldg4(ea + q*4);
    v[q*4+0]=f.x; v[q*4+1]=f.y; v[q*4+2]=f.z; v[q*4+3]=f.w;
  }
  float l0=0.f,l1=0.f,l2=0.f;
  #pragma unroll
  for (int j = 0; j < 16; ++j){
    l0 += v[j]*sP[j*3+0]; l1 += v[j]*sP[j*3+1]; l2 += v[j]*sP[j*3+2];
  }
  int d = ei[E_ + e];
  int p = atomicAdd(&cursor[d], 1);
  src_s[p] = ei[e];
  dst_s[p] = d;
  el_s[p*3+0] = l0; el_s[p*3+1] = l1; el_s[p*3+2] = l2;
}

// ---------------- per-step kernels ----------------

// fused BN(hsrc) + xw = bn(x)@Wg via MFMA + alpha dots.
// Also persists the BN'd activation as bf16 A-fragments (fr) for k_final,
// and stores xw in [n][c*4+h] layout (one 8B gather per lane in k_agg).
__global__ __launch_bounds__(256) void k_xw(
    const float* __restrict__ hsrc,
    const float* __restrict__ bn_stats,
    const float* __restrict__ gamma, const float* __restrict__ beta,
    int gidx, int bn,
    const unsigned short* __restrict__ fG,
    const float* __restrict__ a_src, const float* __restrict__ a_dst,
    unsigned short* __restrict__ xw,
    float* __restrict__ asrc, float* __restrict__ adst,
    unsigned short* __restrict__ fr)
{
  __shared__ short sAf[8*64*8];        // A-frag bf16, 8 KB
  __shared__ unsigned short sXW[64*196];
  __shared__ float sSc[64], sSh[64];
  const int t = threadIdx.x;
  const int row0 = blockIdx.x * 64;
  if (t < 64){
    float sc = 1.f, sh = 0.f;
    if (bn){
      float mu  = bn_stats[t] * (1.0f/30000.0f);
      float var = bn_stats[64+t] * (1.0f/30000.0f) - mu*mu;
      float rs = rsqrtf(var + 1e-5f);
      sc = gamma[gidx*64 + t] * rs;
      sh = beta[gidx*64 + t] - mu*sc;
    }
    sSc[t] = sc; sSh[t] = sh;
  }
  __syncthreads();
  {
    const int lr = t >> 4, k4 = (t & 15) * 4;
    const float sc0=sSc[k4],sc1=sSc[k4+1],sc2=sSc[k4+2],sc3=sSc[k4+3];
    const float sh0=sSh[k4],sh1=sSh[k4+1],sh2=sSh[k4+2],sh3=sSh[k4+3];
    const int kt = k4 >> 5, lanew = lr + (((k4>>3)&3)<<4), j0 = k4 & 7;
    #pragma unroll
    for (int i = 0; i < 4; ++i){
      int r = lr + i*16, gr = row0 + r;
      float4 v = make_float4(0.f,0.f,0.f,0.f);
      if (gr < N_){
        v = ldg4(hsrc + (size_t)gr*64 + k4);
        v.x = fmaf(v.x, sc0, sh0); v.y = fmaf(v.y, sc1, sh1);
        v.z = fmaf(v.z, sc2, sh2); v.w = fmaf(v.w, sc3, sh3);
      }
      ushort4 pk; pk.x=f2bf(v.x); pk.y=f2bf(v.y); pk.z=f2bf(v.z); pk.w=f2bf(v.w);
      *reinterpret_cast<ushort4*>(&sAf[((i*2+kt)*64 + lanew)*8 + j0]) = pk;
    }
  }
  __syncthreads();
  // persist the fragment tile (this block's 64 rows of the feature slot)
  {
    bf16x8 v0 = *reinterpret_cast<bf16x8*>(&sAf[t*8]);
    bf16x8 v1 = *reinterpret_cast<bf16x8*>(&sAf[2048 + t*8]);
    bf16x8* g = reinterpret_cast<bf16x8*>(fr + (size_t)blockIdx.x*4096);
    g[t] = v0; g[256 + t] = v1;
  }
  const int w = t >> 6, l = t & 63, q = l >> 4, b = l & 15;
  f32x4 acc[12];
  #pragma unroll
  for (int nt = 0; nt < 12; ++nt) acc[nt] = (f32x4){0.f,0.f,0.f,0.f};
  bf16x8 a0 = *reinterpret_cast<bf16x8*>(&sAf[((w*2+0)*64 + l)*8]);
  bf16x8 a1 = *reinterpret_cast<bf16x8*>(&sAf[((w*2+1)*64 + l)*8]);
  #pragma unroll
  for (int nt = 0; nt < 12; ++nt){
    bf16x8 b0 = *reinterpret_cast<const bf16x8*>(fG + (size_t)((nt*2+0)*64 + l)*8);
    bf16x8 b1 = *reinterpret_cast<const bf16x8*>(fG + (size_t)((nt*2+1)*64 + l)*8);
    acc[nt] = __builtin_amdgcn_mfma_f32_16x16x32_bf16(a0, b0, acc[nt], 0, 0, 0);
    acc[nt] = __builtin_amdgcn_mfma_f32_16x16x32_bf16(a1, b1, acc[nt], 0, 0, 0);
  }
  // attention dots: asrc/adst per (row, head)
  float asl[3][4], adl[3][4];
  #pragma unroll
  for (int h = 0; h < 3; ++h)
    #pragma unroll
    for (int u = 0; u < 4; ++u){
      asl[h][u] = a_src[h*64 + u*16 + b];
      adl[h][u] = a_dst[h*64 + u*16 + b];
    }
  #pragma unroll
  for (int r = 0; r < 4; ++r){
    int gr = row0 + w*16 + q*4 + r;
    #pragma unroll
    for (int h = 0; h < 3; ++h){
      float s = 0.f, d = 0.f;
      #pragma unroll
      for (int u = 0; u < 4; ++u){
        s = fmaf(acc[4*h+u][r], asl[h][u], s);
        d = fmaf(acc[4*h+u][r], adl[h][u], d);
      }
      s += __shfl_xor(s,1); s += __shfl_xor(s,2); s += __shfl_xor(s,4); s += __shfl_xor(s,8);
      d += __shfl_xor(d,1); d += __shfl_xor(d,2); d += __shfl_xor(d,4); d += __shfl_xor(d,8);
      if (b == h && gr < N_){ asrc[gr*3+h] = s; adst[gr*3+h] = d; }
    }
  }
  // xw -> LDS bf16 -> coalesced global in [n][c*4+h] layout
  #pragma unroll
  for (int nt = 0; nt < 12; ++nt){
    int col = nt*16 + b;
    #pragma unroll
    for (int r = 0; r < 4; ++r)
      sXW[(w*16 + q*4 + r)*196 + col] = f2bf(acc[nt][r]);
  }
  __syncthreads();
  #pragma unroll
  for (int i = 0; i < 16; ++i){
    int id = i*256 + t;                 // 4096 (row, c) pairs
    int row = id >> 6, c2 = id & 63, gr = row0 + row;
    if (gr < N_){
      ushort4 pv;
      pv.x = sXW[row*196 + c2];
      pv.y = sXW[row*196 + 64 + c2];
      pv.z = sXW[row*196 + 128 + c2];
      pv.w = 0;
      *reinterpret_cast<ushort4*>(xw + ((size_t)gr << 8) + (c2 << 2)) = pv;
    }
  }
}

// edge-parallel attention weights: att = exp(leaky_relu(asrc+adst+el))
// (no max-subtraction: algebraically identical softmax; logits are O(+-8))
__global__ void k_att(const int* __restrict__ src_s, const int* __restrict__ dst_s,
                      const float* __restrict__ el_s,
                      const float* __restrict__ asrc, const float* __restrict__ adst,
                      float* __restrict__ att_s){
  int p = blockIdx.x*256 + threadIdx.x;
  if (p >= E_) return;
  int s = src_s[p], d = dst_s[p];
  #pragma unroll
  for (int h = 0; h < 3; ++h){
    float l = asrc[s*3+h] + adst[d*3+h] + el_s[p*3+h];
    l = l > 0.f ? l : 0.2f*l;
    att_s[p*3+h] = __expf(l);
  }
}

// per-node weighted aggregation: one wave per node, one 8B gather per edge.
// block 0 zeroes bn_stats for the following k_gru.
__global__ __launch_bounds__(256) void k_agg(
    const int* __restrict__ row_ptr, const int* __restrict__ src_s,
    const float* __restrict__ att_s,
    const unsigned short* __restrict__ xw,
    const float* __restrict__ bg,
    float* __restrict__ mbuf, float* __restrict__ bn_stats)
{
  if (blockIdx.x == 0 && threadIdx.x < 128) bn_stats[threadIdx.x] = 0.f;
  int n = blockIdx.x*4 + (threadIdx.x >> 6);
  int c = threadIdx.x & 63;
  if (n >= N_) return;
  int p0 = row_ptr[n], p1 = row_ptr[n+1];
  float d0 = 0.f, d1 = 0.f, d2 = 0.f;
  float a0 = 0.f, a1 = 0.f, a2 = 0.f;
  int p = p0;
  for (; p + 4 <= p1; p += 4){
    int sA = src_s[p], sB = src_s[p+1], sC = src_s[p+2], sD = src_s[p+3];
    ushort4 gA = *reinterpret_cast<const ushort4*>(xw + ((size_t)sA << 8) + (c << 2));
    ushort4 gB = *reinterpret_cast<const ushort4*>(xw + ((size_t)sB << 8) + (c << 2));
    ushort4 gC = *reinterpret_cast<const ushort4*>(xw + ((size_t)sC << 8) + (c << 2));
    ushort4 gD = *reinterpret_cast<const ushort4*>(xw + ((size_t)sD << 8) + (c << 2));
    float wA0 = att_s[p*3+0],  wA1 = att_s[p*3+1],  wA2 = att_s[p*3+2];
    float wB0 = att_s[p*3+3],  wB1 = att_s[p*3+4],  wB2 = att_s[p*3+5];
    float wC0 = att_s[p*3+6],  wC1 = att_s[p*3+7],  wC2 = att_s[p*3+8];
    float wD0 = att_s[p*3+9],  wD1 = att_s[p*3+10], wD2 = att_s[p*3+11];
    d0 += (wA0 + wB0) + (wC0 + wD0);
    d1 += (wA1 + wB1) + (wC1 + wD1);
    d2 += (wA2 + wB2) + (wC2 + wD2);
    a0 = fmaf(wA0, bf2f(gA.x), a0); a1 = fmaf(wA1, bf2f(gA.y), a1); a2 = fmaf(wA2, bf2f(gA.z), a2);
    a0 = fmaf(wB0, bf2f(gB.x), a0); a1 = fmaf(wB1, bf2f(gB.y), a1); a2 = fmaf(wB2, bf2f(gB.z), a2);
    a0 = fmaf(wC0, bf2f(gC.x), a0); a1 = fmaf(wC1, bf2f(gC.y), a1); a2 = fmaf(wC2, bf2f(gC.z), a2);
    a0 = fmaf(wD0, bf2f(gD.x), a0); a1 = fmaf(wD1, bf2f(gD.y), a1); a2 = fmaf(wD2, bf2f(gD.z), a2);
  }
  for (; p < p1; ++p){
    int s = src_s[p];
    ushort4 g = *reinterpret_cast<const ushort4*>(xw + ((size_t)s << 8) + (c << 2));
    float w0 = att_s[p*3+0], w1 = att_s[p*3+1], w2 = att_s[p*3+2];
    d0 += w0; d1 += w1; d2 += w2;
    a0 = fmaf(w0, bf2f(g.x), a0);
    a1 = fmaf(w1, bf2f(g.y), a1);
    a2 = fmaf(w2, bf2f(g.z), a2);
  }
  float mp = (a0/(d0+1e-16f) + a1/(d1+1e-16f) + a2/(d2+1e-16f)) * (1.0f/3.0f) + bg[c];
  mbuf[(size_t)n*64 + c] = mp > 0.f ? mp : (__expf(mp) - 1.0f);  // celu
}

// GRU step via MFMA: gi = m@Wih^T, gh = h@Whh^T, gates, h update; BN stats.
__global__ __launch_bounds__(256) void k_gru(
    const float* __restrict__ mbuf, const float* __restrict__ hsrc,
    float* __restrict__ hbuf,
    const unsigned short* __restrict__ fI, const unsigned short* __restrict__ fH,
    const float* __restrict__ bih, const float* __restrict__ bhh,
    float* __restrict__ bn_stats)
{
  __shared__ short sMf[8*64*8];
  __shared__ short sHf[8*64*8];
  __shared__ float sH[64][68];
  __shared__ float sStat[128];
  const int t = threadIdx.x;
  const int row0 = blockIdx.x * 64;
  if (t < 128) sStat[t] = 0.f;
  {
    const int lr = t >> 4, k4 = (t & 15) * 4;
    const int kt = k4 >> 5, lanew = lr + (((k4>>3)&3)<<4), j0 = k4 & 7;
    #pragma unroll
    for (int i = 0; i < 4; ++i){
      int r = lr + i*16, gr = row0 + r;
      float4 vm = make_float4(0.f,0.f,0.f,0.f), vh = vm;
      if (gr < N_){ vm = ldg4(mbuf + (size_t)gr*64 + k4); vh = ldg4(hsrc + (size_t)gr*64 + k4); }
      ushort4 pm; pm.x=f2bf(vm.x); pm.y=f2bf(vm.y); pm.z=f2bf(vm.z); pm.w=f2bf(vm.w);
      ushort4 ph; ph.x=f2bf(vh.x); ph.y=f2bf(vh.y); ph.z=f2bf(vh.z); ph.w=f2bf(vh.w);
      *reinterpret_cast<ushort4*>(&sMf[((i*2+kt)*64 + lanew)*8 + j0]) = pm;
      *reinterpret_cast<ushort4*>(&sHf[((i*2+kt)*64 + lanew)*8 + j0]) = ph;
      sH[r][k4+0]=vh.x; sH[r][k4+1]=vh.y; sH[r][k4+2]=vh.z; sH[r][k4+3]=vh.w;
    }
  }
  __syncthreads();
  const int w = t >> 6, l = t & 63, q = l >> 4, b = l & 15;
  f32x4 aI[12], aH[12];
  #pragma unroll
  for (int nt = 0; nt < 12; ++nt){ aI[nt] = (f32x4){0.f,0.f,0.f,0.f}; aH[nt] = (f32x4){0.f,0.f,0.f,0.f}; }
  bf16x8 am0 = *reinterpret_cast<bf16x8*>(&sMf[((w*2+0)*64 + l)*8]);
  bf16x8 am1 = *reinterpret_cast<bf16x8*>(&sMf[((w*2+1)*64 + l)*8]);
  bf16x8 ah0 = *reinterpret_cast<bf16x8*>(&sHf[((w*2+0)*64 + l)*8]);
  bf16x8 ah1 = *reinterpret_cast<bf16x8*>(&sHf[((w*2+1)*64 + l)*8]);
  #pragma unroll
  for (int nt = 0; nt < 12; ++nt){
    bf16x8 bI0 = *reinterpret_cast<const bf16x8*>(fI + (size_t)((nt*2+0)*64 + l)*8);
    bf16x8 bI1 = *reinterpret_cast<const bf16x8*>(fI + (size_t)((nt*2+1)*64 + l)*8);
    bf16x8 bH0 = *reinterpret_cast<const bf16x8*>(fH + (size_t)((nt*2+0)*64 + l)*8);
    bf16x8 bH1 = *reinterpret_cast<const bf16x8*>(fH + (size_t)((nt*2+1)*64 + l)*8);
    aI[nt] = __builtin_amdgcn_mfma_f32_16x16x32_bf16(am0, bI0, aI[nt], 0, 0, 0);
    aI[nt] = __builtin_amdgcn_mfma_f32_16x16x32_bf16(am1, bI1, aI[nt], 0, 0, 0);
    aH[nt] = __builtin_amdgcn_mfma_f32_16x16x32_bf16(ah0, bH0, aH[nt], 0, 0, 0);
    aH[nt] = __builtin_amdgcn_mfma_f32_16x16x32_bf16(ah1, bH1, aH[nt], 0, 0, 0);
  }
  float s1[4] = {0.f,0.f,0.f,0.f}, s2[4] = {0.f,0.f,0.f,0.f};
  #pragma unroll
  for (int tt = 0; tt < 4; ++tt){
    int c = tt*16 + b;
    float bir = bih[c], biz = bih[64+c], bin = bih[128+c];
    float bhr = bhh[c], bhz = bhh[64+c], bhn = bhh[128+c];
    #pragma unroll
    for (int r = 0; r < 4; ++r){
      int row = w*16 + q*4 + r, gr = row0 + row;
      float rg = sigmoidf_(aI[tt][r]   + bir + aH[tt][r]   + bhr);
      float zg = sigmoidf_(aI[tt+4][r] + biz + aH[tt+4][r] + bhz);
      float ng = tanhf(aI[tt+8][r] + bin + rg*(aH[tt+8][r] + bhn));
      float ho = sH[row][c];
      float hv = (1.f - zg)*ng + zg*ho;
      if (gr < N_){
        hbuf[(size_t)gr*64 + c] = hv;
        s1[tt] += hv; s2[tt] += hv*hv;
      }
    }
  }
  #pragma unroll
  for (int tt = 0; tt < 4; ++tt){
    float v = s1[tt];
    v += __shfl_xor(v, 16); v += __shfl_xor(v, 32);
    float u = s2[tt];
    u += __shfl_xor(u, 16); u += __shfl_xor(u, 32);
    if (q == 0){
      atomicAdd(&sStat[tt*16 + b], v);
      atomicAdd(&sStat[64 + tt*16 + b], u);
    }
  }
  __syncthreads();
  if (t < 128) atomicAdd(&bn_stats[t], sStat[t]);
}

// out = [frag slots 0..5 | bn(hbuf)] @ Wlin + blin via MFMA; slots read as
// bf16 fragments directly from global (no staging), slot 6 staged via LDS.
__global__ __launch_bounds__(256) void k_final(
    const unsigned short* __restrict__ ff, const float* __restrict__ hbuf,
    const float* __restrict__ bn_stats,
    const float* __restrict__ gamma, const float* __restrict__ beta,
    const unsigned short* __restrict__ fL, const float* __restrict__ blin,
    float* __restrict__ out)
{
  __shared__ short sAf[8*64*8];
  __shared__ float sSc[64], sSh[64];
  const int t = threadIdx.x;
  const int row0 = blockIdx.x * 64;
  if (t < 64){
    float mu  = bn_stats[t] * (1.0f/30000.0f);
    float var = bn_stats[64+t] * (1.0f/30000.0f) - mu*mu;
    float rs = rsqrtf(var + 1e-5f);
    float sc = gamma[5*64 + t] * rs;
    sSc[t] = sc;
    sSh[t] = beta[5*64 + t] - mu*sc;
  }
  __syncthreads();
  const int w = t >> 6, l = t & 63, q = l >> 4, b = l & 15;
  const int lr = t >> 4, k4 = (t & 15) * 4;
  const int kt = k4 >> 5, lanew = lr + (((k4>>3)&3)<<4), j0 = k4 & 7;
  // stage slot 6 = bn(hbuf)
  {
    #pragma unroll
    for (int i = 0; i < 4; ++i){
      int r = lr + i*16, gr = row0 + r;
      float4 v = make_float4(0.f,0.f,0.f,0.f);
      if (gr < N_){
        v = ldg4(hbuf + (size_t)gr*64 + k4);
        v.x = fmaf(v.x, sSc[k4+0], sSh[k4+0]);
        v.y = fmaf(v.y, sSc[k4+1], sSh[k4+1]);
        v.z = fmaf(v.z, sSc[k4+2], sSh[k4+2]);
        v.w = fmaf(v.w, sSc[k4+3], sSh[k4+3]);
      }
      ushort4 pk; pk.x=f2bf(v.x); pk.y=f2bf(v.y); pk.z=f2bf(v.z); pk.w=f2bf(v.w);
      *reinterpret_cast<ushort4*>(&sAf[((i*2+kt)*64 + lanew)*8 + j0]) = pk;
    }
  }
  __syncthreads();
  f32x4 acc[4];
  #pragma unroll
  for (int nt = 0; nt < 4; ++nt) acc[nt] = (f32x4){0.f,0.f,0.f,0.f};
  const unsigned short* fb = ff + (size_t)blockIdx.x*4096;
  #pragma unroll
  for (int kc = 0; kc < 6; ++kc){
    const unsigned short* fs = fb + (size_t)kc*GB_*4096;
    bf16x8 a0 = *reinterpret_cast<const bf16x8*>(fs + (w*2+0)*512 + l*8);
    bf16x8 a1 = *reinterpret_cast<const bf16x8*>(fs + (w*2+1)*512 + l*8);
    #pragma unroll
    for (int nt = 0; nt < 4; ++nt){
      bf16x8 b0 = *reinterpret_cast<const bf16x8*>(fL + (size_t)((nt*14 + kc*2+0)*64 + l)*8);
      bf16x8 b1 = *reinterpret_cast<const bf16x8*>(fL + (size_t)((nt*14 + kc*2+1)*64 + l)*8);
      acc[nt] = __builtin_amdgcn_mfma_f32_16x16x32_bf16(a0, b0, acc[nt], 0, 0, 0);
      acc[nt] = __builtin_amdgcn_mfma_f32_16x16x32_bf16(a1, b1, acc[nt], 0, 0, 0);
    }
  }
  {
    bf16x8 a0 = *reinterpret_cast<bf16x8*>(&sAf[((w*2+0)*64 + l)*8]);
    bf16x8 a1 = *reinterpret_cast<bf16x8*>(&sAf[((w*2+1)*64 + l)*8]);
    #pragma unroll
    for (int nt = 0; nt < 4; ++nt){
      bf16x8 b0 = *reinterpret_cast<const bf16x8*>(fL + (size_t)((nt*14 + 12)*64 + l)*8);
      bf16x8 b1 = *reinterpret_cast<const bf16x8*>(fL + (size_t)((nt*14 + 13)*64 + l)*8);
      acc[nt] = __builtin_amdgcn_mfma_f32_16x16x32_bf16(a0, b0, acc[nt], 0, 0, 0);
      acc[nt] = __builtin_amdgcn_mfma_f32_16x16x32_bf16(a1, b1, acc[nt], 0, 0, 0);
    }
  }
  #pragma unroll
  for (int nt = 0; nt < 4; ++nt){
    int col = nt*16 + b;
    float bl = blin[col];
    #pragma unroll
    for (int r = 0; r < 4; ++r){
      int gr = row0 + w*16 + q*4 + r;
      if (gr < N_) out[(size_t)gr*64 + col] = acc[nt][r] + bl;
    }
  }
}

// ---------------- launch ----------------

extern "C" void kernel_launch(void* const* d_in, const int* in_sizes, int n_in,
                              void* d_out, int out_size, void* d_ws, size_t ws_size,
                              hipStream_t stream) {
  const float* x        = (const float*)d_in[0];
  const int*   ei       = (const int*)  d_in[1];
  const float* edge_attr= (const float*)d_in[2];
  const float* Wg       = (const float*)d_in[3];
  const float* bg       = (const float*)d_in[4];
  const float* a_src    = (const float*)d_in[5];
  const float* a_dst    = (const float*)d_in[6];
  const float* We       = (const float*)d_in[7];
  const float* a_edge   = (const float*)d_in[8];
  const float* Wih      = (const float*)d_in[9];
  const float* Whh      = (const float*)d_in[10];
  const float* bih      = (const float*)d_in[11];
  const float* bhh      = (const float*)d_in[12];
  const float* gamma    = (const float*)d_in[13];
  const float* beta     = (const float*)d_in[14];
  const float* Wlin     = (const float*)d_in[15];
  const float* blin     = (const float*)d_in[16];
  float* out = (float*)d_out;

  char* w = (char*)d_ws;
  auto alloc = [&](size_t bytes) -> void* {
    void* p = (void*)w;
    w += (bytes + 255) & ~(size_t)255;
    return p;
  };
  int*   row_ptr = (int*)  alloc((size_t)(N_+1)*4);
  int*   deg     = (int*)  alloc((size_t)N_*4);
  int*   cursor  = (int*)  alloc((size_t)N_*4);
  int*   partial = (int*)  alloc(128*4);
  int*   src_s   = (int*)  alloc((size_t)E_*4);
  int*   dst_s   = (int*)  alloc((size_t)E_*4);
  float* el_s    = (float*)alloc((size_t)E_*3*4);
  float* att_s   = (float*)alloc((size_t)E_*3*4);
  float* Pw      = (float*)alloc(48*4);
  unsigned short* fG = (unsigned short*)alloc(12288*2);
  unsigned short* fI = (unsigned short*)alloc(12288*2);
  unsigned short* fH = (unsigned short*)alloc(12288*2);
  unsigned short* fL = (unsigned short*)alloc(28672*2);
  unsigned short* xw = (unsigned short*)alloc((size_t)N_*256*2);
  unsigned short* ffrag = (unsigned short*)alloc((size_t)6*GB_*4096*2);
  float* asrc    = (float*)alloc((size_t)N_*3*4);
  float* adst    = (float*)alloc((size_t)N_*3*4);
  float* mbuf    = (float*)alloc((size_t)N_*64*4);
  float* hbuf    = (float*)alloc((size_t)N_*64*4);
  float* bn_stats= (float*)alloc(128*4);

  const int EB = (E_ + 255)/256;       // 1172

  k_wfrag  <<<257 + SCB, 256, 0, stream>>>(Wg, Wih, Whh, Wlin, We, a_edge,
                                           fG, fI, fH, fL, Pw, deg);
  k_hist   <<<EB, 256, 0, stream>>>(ei, deg);
  k_scanA  <<<SCB, 256, 0, stream>>>(deg, partial);
  k_scanB  <<<1, 128, 0, stream>>>(partial, row_ptr);
  k_scanC  <<<SCB, 256, 0, stream>>>(deg, partial, row_ptr, cursor);
  k_scatter<<<EB, 256, 0, stream>>>(ei, edge_attr, Pw, cursor, src_s, dst_s, el_s);

  for (int step = 0; step < 6; ++step){
    const float* hsrc = (step == 0) ? x : hbuf;
    k_xw <<<GB_, 256, 0, stream>>>(hsrc, bn_stats, gamma, beta,
                                   step-1, step > 0 ? 1 : 0,
                                   fG, a_src, a_dst, xw, asrc, adst,
                                   ffrag + (size_t)step*GB_*4096);
    k_att<<<EB, 256, 0, stream>>>(src_s, dst_s, el_s, asrc, adst, att_s);
    k_agg<<<(N_+3)/4, 256, 0, stream>>>(row_ptr, src_s, att_s, xw, bg, mbuf, bn_stats);
    k_gru<<<GB_, 256, 0, stream>>>(mbuf, hsrc, hbuf, fI, fH, bih, bhh, bn_stats);
  }
  k_final<<<GB_, 256, 0, stream>>>(ffrag, hbuf, bn_stats, gamma, beta, fL, blin, out);
}